// Round 1
// baseline (2379.512 us; speedup 1.0000x reference)
//
#include <hip/hip_runtime.h>
#include <math.h>

#define NB 2
#define NS 2048
#define ND 1024
#define NH 16
#define DH 64

// ---------------- Kernel 1: fused QKV projections ----------------
// out[p][b][h][s][e] = sum_d X_p[b][s][d] * W_p[h][d][e] + bias_p[h][e]
// grid: (NS/64, NB*NH, 3), block: 256
__global__ __launch_bounds__(256) void proj_kernel(
    const float* __restrict__ query, const float* __restrict__ key,
    const float* __restrict__ value,
    const float* __restrict__ Wq, const float* __restrict__ bq,
    const float* __restrict__ Wk, const float* __restrict__ bk,
    const float* __restrict__ Wv, const float* __restrict__ bv,
    float* __restrict__ qkv_ws)
{
    const int s0 = blockIdx.x * 64;
    const int bh = blockIdx.y;
    const int b = bh / NH, h = bh % NH;
    const int p = blockIdx.z;
    const float* X    = (p == 0) ? query : (p == 1) ? key : value;
    const float* W    = (p == 0) ? Wq    : (p == 1) ? Wk  : Wv;
    const float* bias = (p == 0) ? bq    : (p == 1) ? bk  : bv;

    __shared__ float Xs[64][36];   // 64 rows x 32 k (padded)
    __shared__ float Ws[32][68];   // 32 k x 64 cols (padded)

    const int t  = threadIdx.x;
    const int tr = t >> 4, tc = t & 15;

    float acc[4][4] = {};

    const float* Xb = X + (size_t)b * NS * ND + (size_t)s0 * ND;
    const float* Wh = W + (size_t)h * ND * DH;

    for (int d0 = 0; d0 < ND; d0 += 32) {
        {   // X tile: 64x32, 8 floats/thread
            int row = t >> 2;
            int col = (t & 3) * 8;
            const float4* src = (const float4*)(Xb + (size_t)row * ND + d0 + col);
            float4 v0 = src[0], v1 = src[1];
            Xs[row][col+0]=v0.x; Xs[row][col+1]=v0.y; Xs[row][col+2]=v0.z; Xs[row][col+3]=v0.w;
            Xs[row][col+4]=v1.x; Xs[row][col+5]=v1.y; Xs[row][col+6]=v1.z; Xs[row][col+7]=v1.w;
        }
        {   // W tile: 32x64, 8 floats/thread
            int row = t >> 3;
            int col = (t & 7) * 8;
            const float4* src = (const float4*)(Wh + (size_t)(d0 + row) * DH + col);
            float4 v0 = src[0], v1 = src[1];
            Ws[row][col+0]=v0.x; Ws[row][col+1]=v0.y; Ws[row][col+2]=v0.z; Ws[row][col+3]=v0.w;
            Ws[row][col+4]=v1.x; Ws[row][col+5]=v1.y; Ws[row][col+6]=v1.z; Ws[row][col+7]=v1.w;
        }
        __syncthreads();
        #pragma unroll
        for (int kk = 0; kk < 32; ++kk) {
            float a0 = Xs[tr*4+0][kk], a1 = Xs[tr*4+1][kk];
            float a2 = Xs[tr*4+2][kk], a3 = Xs[tr*4+3][kk];
            float b0 = Ws[kk][tc*4+0], b1 = Ws[kk][tc*4+1];
            float b2 = Ws[kk][tc*4+2], b3 = Ws[kk][tc*4+3];
            acc[0][0]+=a0*b0; acc[0][1]+=a0*b1; acc[0][2]+=a0*b2; acc[0][3]+=a0*b3;
            acc[1][0]+=a1*b0; acc[1][1]+=a1*b1; acc[1][2]+=a1*b2; acc[1][3]+=a1*b3;
            acc[2][0]+=a2*b0; acc[2][1]+=a2*b1; acc[2][2]+=a2*b2; acc[2][3]+=a2*b3;
            acc[3][0]+=a3*b0; acc[3][1]+=a3*b1; acc[3][2]+=a3*b2; acc[3][3]+=a3*b3;
        }
        __syncthreads();
    }

    // epilogue: + bias, store to qkv_ws[((p*NB+b)*NH+h)*NS + s][e]
    float* outp = qkv_ws + ((((size_t)p * NB + b) * NH + h) * NS + s0) * DH;
    #pragma unroll
    for (int i = 0; i < 4; ++i) {
        #pragma unroll
        for (int j = 0; j < 4; ++j) {
            int r = tr*4 + i, c = tc*4 + j;
            outp[(size_t)r * DH + c] = acc[i][j] + bias[h * DH + c];
        }
    }
}

// ---------------- Kernel 2: flash attention (fp32) ----------------
// one thread = one query row; block = 256 rows; K/V tiles 64x64 in LDS
// grid: (NS/256, NB*NH), block: 256
__global__ __launch_bounds__(256) void attn_kernel(
    const float* __restrict__ qkv_ws, float* __restrict__ attn_ws)
{
    const int s  = blockIdx.x * 256 + threadIdx.x;
    const int bh = blockIdx.y;

    const float* qp    = qkv_ws + ((size_t)0 * NB * NH + bh) * (size_t)NS * DH + (size_t)s * DH;
    const float* kbase = qkv_ws + ((size_t)1 * NB * NH + bh) * (size_t)NS * DH;
    const float* vbase = qkv_ws + ((size_t)2 * NB * NH + bh) * (size_t)NS * DH;

    float4 q[16];
    {
        const float4* qv = (const float4*)qp;
        #pragma unroll
        for (int i = 0; i < 16; ++i) q[i] = qv[i];
    }

    float4 o[16];
    #pragma unroll
    for (int i = 0; i < 16; ++i) o[i] = make_float4(0.f, 0.f, 0.f, 0.f);
    float m = -INFINITY, l = 0.f;

    __shared__ float Ks[64][64];
    __shared__ float Vs[64][64];

    for (int jt = 0; jt < NS; jt += 64) {
        __syncthreads();
        {   // stage K/V tiles: 16 floats each per thread
            int row = threadIdx.x >> 2;
            int col = (threadIdx.x & 3) * 16;
            const float4* ksrc = (const float4*)(kbase + (size_t)(jt + row) * DH + col);
            const float4* vsrc = (const float4*)(vbase + (size_t)(jt + row) * DH + col);
            #pragma unroll
            for (int u = 0; u < 4; ++u) {
                *(float4*)&Ks[row][col + u*4] = ksrc[u];
                *(float4*)&Vs[row][col + u*4] = vsrc[u];
            }
        }
        __syncthreads();

        #pragma unroll
        for (int half = 0; half < 2; ++half) {
            float p[32];
            float mt = -INFINITY;
            #pragma unroll
            for (int j = 0; j < 32; ++j) {
                const int jj = half * 32 + j;
                float acc = 0.f;
                #pragma unroll
                for (int d4 = 0; d4 < 16; ++d4) {
                    float4 kk4 = *(const float4*)&Ks[jj][d4 * 4];
                    acc += q[d4].x * kk4.x + q[d4].y * kk4.y
                         + q[d4].z * kk4.z + q[d4].w * kk4.w;
                }
                acc *= 0.125f;   // 1/sqrt(64)
                p[j] = acc;
                mt = fmaxf(mt, acc);
            }
            float mnew  = fmaxf(m, mt);
            float scale = expf(m - mnew);   // first tile: exp(-inf)=0
            l *= scale;
            #pragma unroll
            for (int d4 = 0; d4 < 16; ++d4) {
                o[d4].x *= scale; o[d4].y *= scale; o[d4].z *= scale; o[d4].w *= scale;
            }
            m = mnew;
            #pragma unroll
            for (int j = 0; j < 32; ++j) { p[j] = expf(p[j] - mnew); l += p[j]; }
            #pragma unroll
            for (int j = 0; j < 32; ++j) {
                const int jj = half * 32 + j;
                const float pj = p[j];
                #pragma unroll
                for (int d4 = 0; d4 < 16; ++d4) {
                    float4 vv = *(const float4*)&Vs[jj][d4 * 4];
                    o[d4].x += pj * vv.x; o[d4].y += pj * vv.y;
                    o[d4].z += pj * vv.z; o[d4].w += pj * vv.w;
                }
            }
        }
    }

    const float inv = 1.f / l;
    float* op = attn_ws + (size_t)bh * NS * DH + (size_t)s * DH;
    #pragma unroll
    for (int d4 = 0; d4 < 16; ++d4) {
        float4 r;
        r.x = o[d4].x * inv; r.y = o[d4].y * inv;
        r.z = o[d4].z * inv; r.w = o[d4].w * inv;
        *(float4*)&op[d4 * 4] = r;
    }
}

// ---------------- Kernel 3: output projection ----------------
// out[b][s][c] = sum_f cat[b][s][f] * Wo[f][c] + bo[c],
// cat[b][s][h*64+e] = attn_ws[(b*NH+h)*NS + s][e]
// grid: (NB*NS/64, ND/64), block: 256
__global__ __launch_bounds__(256) void out_kernel(
    const float* __restrict__ attn_ws, const float* __restrict__ Wo,
    const float* __restrict__ bo, float* __restrict__ out)
{
    const int r0 = blockIdx.x * 64;
    const int c0 = blockIdx.y * 64;

    __shared__ float As[64][36];
    __shared__ float Bs[32][68];

    const int t  = threadIdx.x;
    const int tr = t >> 4, tc = t & 15;

    float acc[4][4] = {};

    for (int f0 = 0; f0 < NH * DH; f0 += 32) {
        const int h  = f0 >> 6;      // 32-chunks stay within one head
        const int e0 = f0 & 63;
        {   // cat tile 64x32
            int row = t >> 2;
            int col = (t & 3) * 8;
            int gr = r0 + row;
            int b = gr >> 11, s = gr & (NS - 1);
            const float* src = attn_ws + ((size_t)(b * NH + h) * NS + s) * DH + e0 + col;
            float4 v0 = *(const float4*)src;
            float4 v1 = *(const float4*)(src + 4);
            As[row][col+0]=v0.x; As[row][col+1]=v0.y; As[row][col+2]=v0.z; As[row][col+3]=v0.w;
            As[row][col+4]=v1.x; As[row][col+5]=v1.y; As[row][col+6]=v1.z; As[row][col+7]=v1.w;
        }
        {   // Wo tile 32x64
            int row = t >> 3;
            int col = (t & 7) * 8;
            const float* src = Wo + (size_t)(f0 + row) * ND + c0 + col;
            float4 v0 = *(const float4*)src;
            float4 v1 = *(const float4*)(src + 4);
            Bs[row][col+0]=v0.x; Bs[row][col+1]=v0.y; Bs[row][col+2]=v0.z; Bs[row][col+3]=v0.w;
            Bs[row][col+4]=v1.x; Bs[row][col+5]=v1.y; Bs[row][col+6]=v1.z; Bs[row][col+7]=v1.w;
        }
        __syncthreads();
        #pragma unroll
        for (int kk = 0; kk < 32; ++kk) {
            float a0 = As[tr*4+0][kk], a1 = As[tr*4+1][kk];
            float a2 = As[tr*4+2][kk], a3 = As[tr*4+3][kk];
            float b0 = Bs[kk][tc*4+0], b1 = Bs[kk][tc*4+1];
            float b2 = Bs[kk][tc*4+2], b3 = Bs[kk][tc*4+3];
            acc[0][0]+=a0*b0; acc[0][1]+=a0*b1; acc[0][2]+=a0*b2; acc[0][3]+=a0*b3;
            acc[1][0]+=a1*b0; acc[1][1]+=a1*b1; acc[1][2]+=a1*b2; acc[1][3]+=a1*b3;
            acc[2][0]+=a2*b0; acc[2][1]+=a2*b1; acc[2][2]+=a2*b2; acc[2][3]+=a2*b3;
            acc[3][0]+=a3*b0; acc[3][1]+=a3*b1; acc[3][2]+=a3*b2; acc[3][3]+=a3*b3;
        }
        __syncthreads();
    }

    #pragma unroll
    for (int i = 0; i < 4; ++i) {
        #pragma unroll
        for (int j = 0; j < 4; ++j) {
            int gr = r0 + tr*4 + i;
            int c  = c0 + tc*4 + j;
            out[(size_t)gr * ND + c] = acc[i][j] + bo[c];
        }
    }
}

extern "C" void kernel_launch(void* const* d_in, const int* in_sizes, int n_in,
                              void* d_out, int out_size, void* d_ws, size_t ws_size,
                              hipStream_t stream) {
    const float* query = (const float*)d_in[0];
    const float* key_  = (const float*)d_in[1];
    const float* value = (const float*)d_in[2];
    const float* Wq = (const float*)d_in[3];
    const float* bq = (const float*)d_in[4];
    const float* Wk = (const float*)d_in[5];
    const float* bk = (const float*)d_in[6];
    const float* Wv = (const float*)d_in[7];
    const float* bv = (const float*)d_in[8];
    const float* Wo = (const float*)d_in[9];
    const float* bo = (const float*)d_in[10];
    float* out = (float*)d_out;

    float* qkv_ws  = (float*)d_ws;                                   // [3][B][H][S][64]
    float* attn_ws = qkv_ws + (size_t)3 * NB * NH * NS * DH;         // [B][H][S][64]

    dim3 g1(NS / 64, NB * NH, 3);
    proj_kernel<<<g1, 256, 0, stream>>>(query, key_, value, Wq, bq, Wk, bk, Wv, bv, qkv_ws);

    dim3 g2(NS / 256, NB * NH);
    attn_kernel<<<g2, 256, 0, stream>>>(qkv_ws, attn_ws);

    dim3 g3((NB * NS) / 64, ND / 64);
    out_kernel<<<g3, 256, 0, stream>>>(attn_ws, Wo, bo, out);
}

// Round 2
// 646.499 us; speedup vs baseline: 3.6806x; 3.6806x over previous
//
#include <hip/hip_runtime.h>
#include <math.h>

#define NB 2
#define NS 2048
#define ND 1024
#define NH 16
#define DH 64

typedef __attribute__((ext_vector_type(8))) short bf16x8;
typedef __attribute__((ext_vector_type(4))) float f32x4;
typedef __attribute__((ext_vector_type(4))) unsigned short ushort4t;
typedef __attribute__((ext_vector_type(8))) unsigned short ushort8t;
typedef unsigned short ushort;

static __device__ __forceinline__ ushort f2bf(float f) {
    union { float f; unsigned u; } v; v.f = f;
    unsigned r = (v.u + 0x7FFFu + ((v.u >> 16) & 1u)) >> 16;
    return (ushort)r;
}

// ---------------- Kernel 1: fused QKV projections (fp32 math) ----------------
// Q out: bf16 [bh][s][64], pre-scaled by 1/8.  K out: bf16 [bh][s][64].
// V out: bf16 TRANSPOSED [bh][e][S] (via LDS bounce) for MFMA B-operand reads.
// grid: (NS/64, NB*NH, 3), block: 256
__global__ __launch_bounds__(256) void proj_kernel(
    const float* __restrict__ query, const float* __restrict__ key,
    const float* __restrict__ value,
    const float* __restrict__ Wq, const float* __restrict__ bq,
    const float* __restrict__ Wk, const float* __restrict__ bk,
    const float* __restrict__ Wv, const float* __restrict__ bv,
    ushort* __restrict__ q_bf, ushort* __restrict__ k_bf,
    ushort* __restrict__ vT_bf)
{
    const int s0 = blockIdx.x * 64;
    const int bh = blockIdx.y;
    const int b = bh / NH, h = bh % NH;
    const int p = blockIdx.z;
    const float* X    = (p == 0) ? query : (p == 1) ? key : value;
    const float* W    = (p == 0) ? Wq    : (p == 1) ? Wk  : Wv;
    const float* bias = (p == 0) ? bq    : (p == 1) ? bk  : bv;

    __shared__ float Xs[64][36];
    __shared__ float Ws[32][68];
    __shared__ float Vb[64][65];   // transpose bounce for V

    const int t  = threadIdx.x;
    const int tr = t >> 4, tc = t & 15;

    float acc[4][4] = {};

    const float* Xb = X + (size_t)b * NS * ND + (size_t)s0 * ND;
    const float* Wh = W + (size_t)h * ND * DH;

    for (int d0 = 0; d0 < ND; d0 += 32) {
        {   // X tile: 64x32
            int row = t >> 2;
            int col = (t & 3) * 8;
            const float4* src = (const float4*)(Xb + (size_t)row * ND + d0 + col);
            float4 v0 = src[0], v1 = src[1];
            Xs[row][col+0]=v0.x; Xs[row][col+1]=v0.y; Xs[row][col+2]=v0.z; Xs[row][col+3]=v0.w;
            Xs[row][col+4]=v1.x; Xs[row][col+5]=v1.y; Xs[row][col+6]=v1.z; Xs[row][col+7]=v1.w;
        }
        {   // W tile: 32x64
            int row = t >> 3;
            int col = (t & 7) * 8;
            const float4* src = (const float4*)(Wh + (size_t)(d0 + row) * DH + col);
            float4 v0 = src[0], v1 = src[1];
            Ws[row][col+0]=v0.x; Ws[row][col+1]=v0.y; Ws[row][col+2]=v0.z; Ws[row][col+3]=v0.w;
            Ws[row][col+4]=v1.x; Ws[row][col+5]=v1.y; Ws[row][col+6]=v1.z; Ws[row][col+7]=v1.w;
        }
        __syncthreads();
        #pragma unroll
        for (int kk = 0; kk < 32; ++kk) {
            float a0 = Xs[tr*4+0][kk], a1 = Xs[tr*4+1][kk];
            float a2 = Xs[tr*4+2][kk], a3 = Xs[tr*4+3][kk];
            float b0 = Ws[kk][tc*4+0], b1 = Ws[kk][tc*4+1];
            float b2 = Ws[kk][tc*4+2], b3 = Ws[kk][tc*4+3];
            acc[0][0]+=a0*b0; acc[0][1]+=a0*b1; acc[0][2]+=a0*b2; acc[0][3]+=a0*b3;
            acc[1][0]+=a1*b0; acc[1][1]+=a1*b1; acc[1][2]+=a1*b2; acc[1][3]+=a1*b3;
            acc[2][0]+=a2*b0; acc[2][1]+=a2*b1; acc[2][2]+=a2*b2; acc[2][3]+=a2*b3;
            acc[3][0]+=a3*b0; acc[3][1]+=a3*b1; acc[3][2]+=a3*b2; acc[3][3]+=a3*b3;
        }
        __syncthreads();
    }

    if (p < 2) {
        // Q (scaled by 1/8) or K: bf16 [bh][s][64]
        ushort* dst = (p == 0 ? q_bf : k_bf) + ((size_t)bh * NS + s0) * DH;
        const float sc = (p == 0) ? 0.125f : 1.0f;
        #pragma unroll
        for (int i = 0; i < 4; ++i) {
            int r = tr * 4 + i;
            ushort4t pk;
            #pragma unroll
            for (int j = 0; j < 4; ++j)
                pk[j] = f2bf((acc[i][j] + bias[h * DH + tc * 4 + j]) * sc);
            *(ushort4t*)(dst + (size_t)r * DH + tc * 4) = pk;
        }
    } else {
        // V: transpose via LDS, write bf16 [bh][e][S]
        #pragma unroll
        for (int i = 0; i < 4; ++i)
            #pragma unroll
            for (int j = 0; j < 4; ++j)
                Vb[tr*4+i][tc*4+j] = acc[i][j] + bias[h * DH + tc * 4 + j];
        __syncthreads();
        const int e = t >> 2, j0 = (t & 3) * 16;
        ushort* dst = vT_bf + ((size_t)bh * DH + e) * NS + s0 + j0;
        ushort8t w0, w1;
        #pragma unroll
        for (int u = 0; u < 8; ++u) { w0[u] = f2bf(Vb[j0+u][e]); w1[u] = f2bf(Vb[j0+8+u][e]); }
        *(ushort8t*)dst       = w0;
        *(ushort8t*)(dst + 8) = w1;
    }
}

// ---------------- Kernel 2: flash attention, bf16 MFMA ----------------
// grid: (NS/64, NB*NH), block: 256 (4 waves, 16 q-rows each)
__global__ __launch_bounds__(256) void attn_kernel(
    const ushort* __restrict__ q_bf, const ushort* __restrict__ k_bf,
    const ushort* __restrict__ vT_bf, float* __restrict__ attn_ws)
{
    __shared__ __attribute__((aligned(16))) char smem[24576]; // Ks 8K | VTs 8K | Ps 4x2K
    const int t = threadIdx.x;
    const int wid = t >> 6, lane = t & 63;
    const int g = lane >> 4, c = lane & 15;
    const int bh = blockIdx.y;
    const int qrow0 = blockIdx.x * 64 + wid * 16;

    // Q fragments: lane holds Q[qrow0 + c][kc*32 + g*8 .. +8]  (bf16, pre-scaled)
    bf16x8 qf[2];
    {
        const char* qp = (const char*)(q_bf + ((size_t)bh * NS + qrow0 + c) * DH);
        qf[0] = *(const bf16x8*)(qp + g * 16);
        qf[1] = *(const bf16x8*)(qp + 64 + g * 16);
    }

    f32x4 o_acc[4];
    const f32x4 zero = {0.f, 0.f, 0.f, 0.f};
    #pragma unroll
    for (int n = 0; n < 4; ++n) o_acc[n] = zero;
    float m[4], lsum[4];
    #pragma unroll
    for (int r = 0; r < 4; ++r) { m[r] = -INFINITY; lsum[r] = 0.f; }

    const char* kg_base = (const char*)(k_bf + (size_t)bh * NS * DH);
    const char* vg_base = (const char*)(vT_bf + (size_t)bh * DH * NS);

    char* Ks  = smem;
    char* VTs = smem + 8192;
    char* Ps  = smem + 16384 + wid * 2048;

    for (int jt = 0; jt < NS; jt += 64) {
        __syncthreads();
        // stage K tile [key][d] and V^T tile [e][j], both XOR-swizzled
        #pragma unroll
        for (int u = 0; u < 2; ++u) {
            const int chunk = t * 2 + u;
            const int row = chunk >> 3, c16 = chunk & 7;
            const int swz = (c16 * 16) ^ ((row & 7) << 4);
            ushort8t kv = *(const ushort8t*)(kg_base + (size_t)(jt + row) * 128 + c16 * 16);
            *(ushort8t*)(Ks + row * 128 + swz) = kv;
            ushort8t vv = *(const ushort8t*)(vg_base + (size_t)row * (NS * 2) + (size_t)(jt + c16 * 8) * 2);
            *(ushort8t*)(VTs + row * 128 + swz) = vv;
        }
        __syncthreads();

        // QK^T: s_acc[n] holds S[g*4+r][n*16+c]
        f32x4 s_acc[4];
        #pragma unroll
        for (int n = 0; n < 4; ++n) s_acc[n] = zero;
        #pragma unroll
        for (int n = 0; n < 4; ++n) {
            const int key = n * 16 + c;
            #pragma unroll
            for (int kc = 0; kc < 2; ++kc) {
                bf16x8 kf = *(const bf16x8*)(Ks + key * 128 + ((kc * 64 + g * 16) ^ ((key & 7) << 4)));
                s_acc[n] = __builtin_amdgcn_mfma_f32_16x16x32_bf16(qf[kc], kf, s_acc[n], 0, 0, 0);
            }
        }

        // online softmax: row = g*4+r; reduce across 16-lane group + in-lane over n
        float pv[4][4]; // [n][r]
        #pragma unroll
        for (int r = 0; r < 4; ++r) {
            float tm = fmaxf(fmaxf(s_acc[0][r], s_acc[1][r]), fmaxf(s_acc[2][r], s_acc[3][r]));
            tm = fmaxf(tm, __shfl_xor(tm, 1));
            tm = fmaxf(tm, __shfl_xor(tm, 2));
            tm = fmaxf(tm, __shfl_xor(tm, 4));
            tm = fmaxf(tm, __shfl_xor(tm, 8));
            const float mnew = fmaxf(m[r], tm);
            const float sc = __expf(m[r] - mnew);
            m[r] = mnew;
            float rs = 0.f;
            #pragma unroll
            for (int n = 0; n < 4; ++n) {
                float p = __expf(s_acc[n][r] - mnew);
                pv[n][r] = p;
                rs += p;
            }
            rs += __shfl_xor(rs, 1);
            rs += __shfl_xor(rs, 2);
            rs += __shfl_xor(rs, 4);
            rs += __shfl_xor(rs, 8);
            lsum[r] = lsum[r] * sc + rs;
            #pragma unroll
            for (int n = 0; n < 4; ++n) o_acc[n][r] *= sc;
        }

        // P -> per-wave LDS tile [q][j] (bf16, swizzled), wave-synchronous
        #pragma unroll
        for (int n = 0; n < 4; ++n) {
            #pragma unroll
            for (int r = 0; r < 4; ++r) {
                const int q = g * 4 + r;
                *(ushort*)(Ps + q * 128 + ((n * 32 + c * 2) ^ ((q & 7) << 4))) = f2bf(pv[n][r]);
            }
        }

        // PV: o_acc[n] += P[16q x 64j] @ V[64j x e(n*16..)]
        #pragma unroll
        for (int kc = 0; kc < 2; ++kc) {
            bf16x8 pa = *(const bf16x8*)(Ps + c * 128 + ((kc * 64 + g * 16) ^ ((c & 7) << 4)));
            #pragma unroll
            for (int n = 0; n < 4; ++n) {
                const int e = n * 16 + c;
                bf16x8 vf = *(const bf16x8*)(VTs + e * 128 + ((kc * 64 + g * 16) ^ ((e & 7) << 4)));
                o_acc[n] = __builtin_amdgcn_mfma_f32_16x16x32_bf16(pa, vf, o_acc[n], 0, 0, 0);
            }
        }
    }

    float* op = attn_ws + (size_t)bh * NS * DH;
    #pragma unroll
    for (int r = 0; r < 4; ++r) {
        const float inv = 1.0f / lsum[r];
        const int row = qrow0 + g * 4 + r;
        #pragma unroll
        for (int n = 0; n < 4; ++n)
            op[(size_t)row * DH + n * 16 + c] = o_acc[n][r] * inv;
    }
}

// ---------------- Kernel 3: output projection (fp32) ----------------
// grid: (NB*NS/64, ND/64), block: 256
__global__ __launch_bounds__(256) void out_kernel(
    const float* __restrict__ attn_ws, const float* __restrict__ Wo,
    const float* __restrict__ bo, float* __restrict__ out)
{
    const int r0 = blockIdx.x * 64;
    const int c0 = blockIdx.y * 64;

    __shared__ float As[64][36];
    __shared__ float Bs[32][68];

    const int t  = threadIdx.x;
    const int tr = t >> 4, tc = t & 15;

    float acc[4][4] = {};

    for (int f0 = 0; f0 < NH * DH; f0 += 32) {
        const int h  = f0 >> 6;
        const int e0 = f0 & 63;
        {   // cat tile 64x32
            int row = t >> 2;
            int col = (t & 3) * 8;
            int gr = r0 + row;
            int b = gr >> 11, s = gr & (NS - 1);
            const float* src = attn_ws + ((size_t)(b * NH + h) * NS + s) * DH + e0 + col;
            float4 v0 = *(const float4*)src;
            float4 v1 = *(const float4*)(src + 4);
            As[row][col+0]=v0.x; As[row][col+1]=v0.y; As[row][col+2]=v0.z; As[row][col+3]=v0.w;
            As[row][col+4]=v1.x; As[row][col+5]=v1.y; As[row][col+6]=v1.z; As[row][col+7]=v1.w;
        }
        {   // Wo tile 32x64
            int row = t >> 3;
            int col = (t & 7) * 8;
            const float* src = Wo + (size_t)(f0 + row) * ND + c0 + col;
            float4 v0 = *(const float4*)src;
            float4 v1 = *(const float4*)(src + 4);
            Bs[row][col+0]=v0.x; Bs[row][col+1]=v0.y; Bs[row][col+2]=v0.z; Bs[row][col+3]=v0.w;
            Bs[row][col+4]=v1.x; Bs[row][col+5]=v1.y; Bs[row][col+6]=v1.z; Bs[row][col+7]=v1.w;
        }
        __syncthreads();
        #pragma unroll
        for (int kk = 0; kk < 32; ++kk) {
            float a0 = As[tr*4+0][kk], a1 = As[tr*4+1][kk];
            float a2 = As[tr*4+2][kk], a3 = As[tr*4+3][kk];
            float b0 = Bs[kk][tc*4+0], b1 = Bs[kk][tc*4+1];
            float b2 = Bs[kk][tc*4+2], b3 = Bs[kk][tc*4+3];
            acc[0][0]+=a0*b0; acc[0][1]+=a0*b1; acc[0][2]+=a0*b2; acc[0][3]+=a0*b3;
            acc[1][0]+=a1*b0; acc[1][1]+=a1*b1; acc[1][2]+=a1*b2; acc[1][3]+=a1*b3;
            acc[2][0]+=a2*b0; acc[2][1]+=a2*b1; acc[2][2]+=a2*b2; acc[2][3]+=a2*b3;
            acc[3][0]+=a3*b0; acc[3][1]+=a3*b1; acc[3][2]+=a3*b2; acc[3][3]+=a3*b3;
        }
        __syncthreads();
    }

    #pragma unroll
    for (int i = 0; i < 4; ++i) {
        #pragma unroll
        for (int j = 0; j < 4; ++j) {
            int gr = r0 + tr*4 + i;
            int c  = c0 + tc*4 + j;
            out[(size_t)gr * ND + c] = acc[i][j] + bo[c];
        }
    }
}

extern "C" void kernel_launch(void* const* d_in, const int* in_sizes, int n_in,
                              void* d_out, int out_size, void* d_ws, size_t ws_size,
                              hipStream_t stream) {
    const float* query = (const float*)d_in[0];
    const float* key_  = (const float*)d_in[1];
    const float* value = (const float*)d_in[2];
    const float* Wq = (const float*)d_in[3];
    const float* bq = (const float*)d_in[4];
    const float* Wk = (const float*)d_in[5];
    const float* bk = (const float*)d_in[6];
    const float* Wv = (const float*)d_in[7];
    const float* bv = (const float*)d_in[8];
    const float* Wo = (const float*)d_in[9];
    const float* bo = (const float*)d_in[10];
    float* out = (float*)d_out;

    const size_t per = (size_t)NB * NH * NS * DH;  // 4.2M elements
    float*  attn_ws = (float*)d_ws;                 // fp32 [bh][s][64]
    ushort* q_bf  = (ushort*)(attn_ws + per);       // bf16 [bh][s][64], q/8
    ushort* k_bf  = q_bf + per;                     // bf16 [bh][s][64]
    ushort* vT_bf = k_bf + per;                     // bf16 [bh][e][S]

    dim3 g1(NS / 64, NB * NH, 3);
    proj_kernel<<<g1, 256, 0, stream>>>(query, key_, value, Wq, bq, Wk, bk, Wv, bv,
                                        q_bf, k_bf, vT_bf);

    dim3 g2(NS / 64, NB * NH);
    attn_kernel<<<g2, 256, 0, stream>>>(q_bf, k_bf, vT_bf, attn_ws);

    dim3 g3((NB * NS) / 64, ND / 64);
    out_kernel<<<g3, 256, 0, stream>>>(attn_ws, Wo, bo, out);
}

// Round 3
// 307.836 us; speedup vs baseline: 7.7298x; 2.1001x over previous
//
#include <hip/hip_runtime.h>
#include <math.h>

#define NB 2
#define NS 2048
#define ND 1024
#define NH 16
#define DH 64
#define MROWS (NB*NS)     // 4096
#define NCOLS (NH*DH)     // 1024

typedef __attribute__((ext_vector_type(8))) short bf16x8;
typedef __attribute__((ext_vector_type(4))) float f32x4;
typedef __attribute__((ext_vector_type(4))) unsigned short ushort4t;
typedef __attribute__((ext_vector_type(8))) unsigned short ushort8t;
typedef unsigned short ushort;

static __device__ __forceinline__ ushort f2bf(float f) {
    union { float f; unsigned u; } v; v.f = f;
    unsigned r = (v.u + 0x7FFFu + ((v.u >> 16) & 1u)) >> 16;
    return (ushort)r;
}

static __device__ __forceinline__ void gld_lds16(const void* g, void* l) {
    __builtin_amdgcn_global_load_lds(
        (const __attribute__((address_space(1))) void*)g,
        (__attribute__((address_space(3))) void*)l, 16, 0, 0);
}

// ---------------- prep: X (q,k,v inputs) fp32 -> bf16 ----------------
// grid 2048 x 256 : exactly 3 x 4096 x 1024 elements, 8 per thread per tensor
__global__ __launch_bounds__(256) void convert_x(
    const float* __restrict__ q, const float* __restrict__ k,
    const float* __restrict__ v, ushort* __restrict__ X_bf)
{
    const size_t n1 = (size_t)MROWS * ND;
    const size_t off = ((size_t)blockIdx.x * 256 + threadIdx.x) * 8;
    const float* srcs[3] = {q, k, v};
    #pragma unroll
    for (int p = 0; p < 3; ++p) {
        float4 a = *(const float4*)(srcs[p] + off);
        float4 b = *(const float4*)(srcs[p] + off + 4);
        ushort8t w;
        w[0]=f2bf(a.x); w[1]=f2bf(a.y); w[2]=f2bf(a.z); w[3]=f2bf(a.w);
        w[4]=f2bf(b.x); w[5]=f2bf(b.y); w[6]=f2bf(b.z); w[7]=f2bf(b.w);
        *(ushort8t*)(X_bf + (size_t)p * n1 + off) = w;
    }
}

// ---------------- prep: Wq/Wk/Wv [H][D][64] -> bf16 W^T [p][h*64+e][d] ----------------
// grid (16, 16, 3) block 256
__global__ __launch_bounds__(256) void repack_w(
    const float* __restrict__ Wq, const float* __restrict__ Wk,
    const float* __restrict__ Wv, ushort* __restrict__ WT_bf)
{
    const int p = blockIdx.z;
    const float* W = (p == 0) ? Wq : (p == 1) ? Wk : Wv;
    const int h = blockIdx.y, d0 = blockIdx.x * 64;
    __shared__ float tile[64][65];
    const int t = threadIdx.x;
    {
        const int i = t >> 2, e0 = (t & 3) * 16;
        const float* src = W + ((size_t)h * ND + d0 + i) * DH + e0;
        #pragma unroll
        for (int u = 0; u < 4; ++u) {
            float4 v4 = ((const float4*)src)[u];
            tile[i][e0 + u*4 + 0] = v4.x; tile[i][e0 + u*4 + 1] = v4.y;
            tile[i][e0 + u*4 + 2] = v4.z; tile[i][e0 + u*4 + 3] = v4.w;
        }
    }
    __syncthreads();
    {
        const int e = t >> 2, dc = (t & 3) * 16;
        ushort* dst = WT_bf + ((size_t)p * NCOLS + h * 64 + e) * ND + d0 + dc;
        ushort8t w0, w1;
        #pragma unroll
        for (int u = 0; u < 8; ++u) { w0[u] = f2bf(tile[dc+u][e]); w1[u] = f2bf(tile[dc+8+u][e]); }
        *(ushort8t*)dst = w0;
        *(ushort8t*)(dst + 8) = w1;
    }
}

// ---------------- prep: Wo [1024][1024] -> bf16 Wo^T [c][f] ----------------
// grid (16, 16) block 256
__global__ __launch_bounds__(256) void repack_wo(
    const float* __restrict__ Wo, ushort* __restrict__ WoT_bf)
{
    const int f0 = blockIdx.x * 64, c0 = blockIdx.y * 64;
    __shared__ float tile[64][65];
    const int t = threadIdx.x;
    {
        const int i = t >> 2, j0 = (t & 3) * 16;
        const float* src = Wo + (size_t)(f0 + i) * ND + c0 + j0;
        #pragma unroll
        for (int u = 0; u < 4; ++u) {
            float4 v4 = ((const float4*)src)[u];
            tile[i][j0 + u*4 + 0] = v4.x; tile[i][j0 + u*4 + 1] = v4.y;
            tile[i][j0 + u*4 + 2] = v4.z; tile[i][j0 + u*4 + 3] = v4.w;
        }
    }
    __syncthreads();
    {
        const int cl = t >> 2, fc = (t & 3) * 16;
        ushort* dst = WoT_bf + (size_t)(c0 + cl) * ND + f0 + fc;
        ushort8t w0, w1;
        #pragma unroll
        for (int u = 0; u < 8; ++u) { w0[u] = f2bf(tile[fc+u][cl]); w1[u] = f2bf(tile[fc+8+u][cl]); }
        *(ushort8t*)dst = w0;
        *(ushort8t*)(dst + 8) = w1;
    }
}

// ---------------- Kernel: QKV projection GEMM, bf16 MFMA ----------------
// C[4096 x 1024] = X[4096 x 1024] @ W[1024 x 1024] + bias ; scatter per head
// grid (32, 8, 3), block 256 (4 waves, each 64x64 out)
__global__ __launch_bounds__(256) void gemm_qkv(
    const ushort* __restrict__ X_bf, const ushort* __restrict__ WT_bf,
    const float* __restrict__ bq, const float* __restrict__ bk,
    const float* __restrict__ bv, ushort* __restrict__ qkv_bf)
{
    const int p = blockIdx.z;
    const float* bias = (p == 0) ? bq : (p == 1) ? bk : bv;
    const float scale = (p == 0) ? 0.125f : 1.0f;
    const int m0 = blockIdx.x * 128, n0 = blockIdx.y * 128;
    const int t = threadIdx.x, wid = t >> 6, lane = t & 63;
    const int wr = wid >> 1, wc = wid & 1;
    const int c = lane & 15, g = lane >> 4;

    __shared__ ushort ldsA[128 * 64];
    __shared__ ushort ldsB[128 * 64];

    const ushort* Ag = X_bf + (size_t)p * MROWS * ND + (size_t)m0 * ND;
    const ushort* Bg = WT_bf + (size_t)p * NCOLS * ND + (size_t)n0 * ND;

    f32x4 acc[4][4];
    #pragma unroll
    for (int m = 0; m < 4; ++m)
        #pragma unroll
        for (int n = 0; n < 4; ++n)
            acc[m][n] = (f32x4){0.f, 0.f, 0.f, 0.f};

    for (int k0 = 0; k0 < ND; k0 += 64) {
        __syncthreads();
        #pragma unroll
        for (int call = 0; call < 4; ++call) {
            const int chb = wid * 256 + call * 64;
            const int ch = chb + lane;
            const int row = ch >> 3, c16 = ch & 7;
            gld_lds16(Ag + (size_t)row * ND + k0 + c16 * 8, ldsA + (size_t)ch * 8);
            gld_lds16(Bg + (size_t)row * ND + k0 + c16 * 8, ldsB + (size_t)ch * 8);
        }
        __syncthreads();
        #pragma unroll
        for (int kc = 0; kc < 2; ++kc) {
            bf16x8 af[4], bfr[4];
            #pragma unroll
            for (int m = 0; m < 4; ++m)
                af[m] = *(const bf16x8*)(ldsA + (wr*64 + m*16 + c) * 64 + kc*32 + g*8);
            #pragma unroll
            for (int n = 0; n < 4; ++n)
                bfr[n] = *(const bf16x8*)(ldsB + (wc*64 + n*16 + c) * 64 + kc*32 + g*8);
            #pragma unroll
            for (int m = 0; m < 4; ++m)
                #pragma unroll
                for (int n = 0; n < 4; ++n)
                    acc[m][n] = __builtin_amdgcn_mfma_f32_16x16x32_bf16(af[m], bfr[n], acc[m][n], 0, 0, 0);
        }
    }

    ushort* dst = qkv_bf + (size_t)p * ((size_t)NB * NH * NS * DH);
    #pragma unroll
    for (int m = 0; m < 4; ++m) {
        const int gr0 = m0 + wr*64 + m*16 + g*4;
        #pragma unroll
        for (int n = 0; n < 4; ++n) {
            const int gc = n0 + wc*64 + n*16 + c;
            const int h = gc >> 6, e = gc & 63;
            const float bv_ = bias[gc];
            #pragma unroll
            for (int j = 0; j < 4; ++j) {
                const int r = gr0 + j;
                const int b = r >> 11, s = r & (NS - 1);
                dst[(((size_t)b * NH + h) * NS + s) * DH + e] = f2bf((acc[m][n][j] + bv_) * scale);
            }
        }
    }
}

// ---------------- V transpose: [bh][s][64] -> [bh][e][S] ----------------
// grid (8, 32) block 256
__global__ __launch_bounds__(256) void v_transpose(
    const ushort* __restrict__ v_bf, ushort* __restrict__ vT_bf)
{
    const int bh = blockIdx.y, s0 = blockIdx.x * 256;
    __shared__ ushort tile[256][72];
    const int t = threadIdx.x;
    const ushort* src = v_bf + ((size_t)bh * NS + s0) * DH;
    #pragma unroll
    for (int u = 0; u < 8; ++u) {
        const int idx = u * 256 + t;
        const int row = idx >> 3, cc = (idx & 7) * 8;
        *(ushort8t*)&tile[row][cc] = *(const ushort8t*)(src + (size_t)row * DH + cc);
    }
    __syncthreads();
    const int e = t >> 2, sc = (t & 3) * 64;
    ushort* dst = vT_bf + ((size_t)bh * DH + e) * NS + s0 + sc;
    #pragma unroll
    for (int u = 0; u < 8; ++u) {
        ushort8t w;
        #pragma unroll
        for (int x = 0; x < 8; ++x) w[x] = tile[sc + u*8 + x][e];
        *(ushort8t*)(dst + u * 8) = w;
    }
}

// ---------------- Kernel: flash attention, bf16 MFMA ----------------
// grid: (NS/64, NB*NH), block: 256 (4 waves, 16 q-rows each)
__global__ __launch_bounds__(256) void attn_kernel(
    const ushort* __restrict__ q_bf, const ushort* __restrict__ k_bf,
    const ushort* __restrict__ vT_bf, ushort* __restrict__ cat_bf)
{
    __shared__ __attribute__((aligned(16))) char smem[24576]; // Ks 8K | VTs 8K | Ps 4x2K
    const int t = threadIdx.x;
    const int wid = t >> 6, lane = t & 63;
    const int g = lane >> 4, c = lane & 15;
    const int bh = blockIdx.y;
    const int qrow0 = blockIdx.x * 64 + wid * 16;

    bf16x8 qf[2];
    {
        const char* qp = (const char*)(q_bf + ((size_t)bh * NS + qrow0 + c) * DH);
        qf[0] = *(const bf16x8*)(qp + g * 16);
        qf[1] = *(const bf16x8*)(qp + 64 + g * 16);
    }

    f32x4 o_acc[4];
    const f32x4 zero = {0.f, 0.f, 0.f, 0.f};
    #pragma unroll
    for (int n = 0; n < 4; ++n) o_acc[n] = zero;
    float m[4], lsum[4];
    #pragma unroll
    for (int r = 0; r < 4; ++r) { m[r] = -INFINITY; lsum[r] = 0.f; }

    const char* kg_base = (const char*)(k_bf + (size_t)bh * NS * DH);
    const char* vg_base = (const char*)(vT_bf + (size_t)bh * DH * NS);

    char* Ks  = smem;
    char* VTs = smem + 8192;
    char* Ps  = smem + 16384 + wid * 2048;

    for (int jt = 0; jt < NS; jt += 64) {
        __syncthreads();
        #pragma unroll
        for (int u = 0; u < 2; ++u) {
            const int chunk = t * 2 + u;
            const int row = chunk >> 3, c16 = chunk & 7;
            const int swz = (c16 * 16) ^ ((row & 7) << 4);
            ushort8t kv = *(const ushort8t*)(kg_base + (size_t)(jt + row) * 128 + c16 * 16);
            *(ushort8t*)(Ks + row * 128 + swz) = kv;
            ushort8t vv = *(const ushort8t*)(vg_base + (size_t)row * (NS * 2) + (size_t)(jt + c16 * 8) * 2);
            *(ushort8t*)(VTs + row * 128 + swz) = vv;
        }
        __syncthreads();

        f32x4 s_acc[4];
        #pragma unroll
        for (int n = 0; n < 4; ++n) s_acc[n] = zero;
        #pragma unroll
        for (int n = 0; n < 4; ++n) {
            const int key = n * 16 + c;
            #pragma unroll
            for (int kc = 0; kc < 2; ++kc) {
                bf16x8 kf = *(const bf16x8*)(Ks + key * 128 + ((kc * 64 + g * 16) ^ ((key & 7) << 4)));
                s_acc[n] = __builtin_amdgcn_mfma_f32_16x16x32_bf16(qf[kc], kf, s_acc[n], 0, 0, 0);
            }
        }

        float pv[4][4];
        #pragma unroll
        for (int r = 0; r < 4; ++r) {
            float tm = fmaxf(fmaxf(s_acc[0][r], s_acc[1][r]), fmaxf(s_acc[2][r], s_acc[3][r]));
            tm = fmaxf(tm, __shfl_xor(tm, 1));
            tm = fmaxf(tm, __shfl_xor(tm, 2));
            tm = fmaxf(tm, __shfl_xor(tm, 4));
            tm = fmaxf(tm, __shfl_xor(tm, 8));
            const float mnew = fmaxf(m[r], tm);
            const float sc = __expf(m[r] - mnew);
            m[r] = mnew;
            float rs = 0.f;
            #pragma unroll
            for (int n = 0; n < 4; ++n) {
                float pj = __expf(s_acc[n][r] - mnew);
                pv[n][r] = pj;
                rs += pj;
            }
            rs += __shfl_xor(rs, 1);
            rs += __shfl_xor(rs, 2);
            rs += __shfl_xor(rs, 4);
            rs += __shfl_xor(rs, 8);
            lsum[r] = lsum[r] * sc + rs;
            #pragma unroll
            for (int n = 0; n < 4; ++n) o_acc[n][r] *= sc;
        }

        #pragma unroll
        for (int n = 0; n < 4; ++n) {
            #pragma unroll
            for (int r = 0; r < 4; ++r) {
                const int q = g * 4 + r;
                *(ushort*)(Ps + q * 128 + ((n * 32 + c * 2) ^ ((q & 7) << 4))) = f2bf(pv[n][r]);
            }
        }

        #pragma unroll
        for (int kc = 0; kc < 2; ++kc) {
            bf16x8 pa = *(const bf16x8*)(Ps + c * 128 + ((kc * 64 + g * 16) ^ ((c & 7) << 4)));
            #pragma unroll
            for (int n = 0; n < 4; ++n) {
                const int e = n * 16 + c;
                bf16x8 vf = *(const bf16x8*)(VTs + e * 128 + ((kc * 64 + g * 16) ^ ((e & 7) << 4)));
                o_acc[n] = __builtin_amdgcn_mfma_f32_16x16x32_bf16(pa, vf, o_acc[n], 0, 0, 0);
            }
        }
    }

    // write bf16 into cat layout [b*S + s][h*64 + e]
    const int b = bh >> 4, hh = bh & 15;
    ushort* op = cat_bf + (size_t)b * NS * NCOLS + hh * DH;
    #pragma unroll
    for (int r = 0; r < 4; ++r) {
        const float inv = 1.0f / lsum[r];
        const int srow = qrow0 + g * 4 + r;
        #pragma unroll
        for (int n = 0; n < 4; ++n)
            op[(size_t)srow * NCOLS + n * 16 + c] = f2bf(o_acc[n][r] * inv);
    }
}

// ---------------- Kernel: output GEMM, bf16 MFMA, fp32 out ----------------
// out[4096 x 1024] = cat[4096 x 1024] @ Wo[1024 x 1024] + bo
// grid (32, 8), block 256
__global__ __launch_bounds__(256) void gemm_out(
    const ushort* __restrict__ cat_bf, const ushort* __restrict__ WoT_bf,
    const float* __restrict__ bo, float* __restrict__ out)
{
    const int m0 = blockIdx.x * 128, n0 = blockIdx.y * 128;
    const int t = threadIdx.x, wid = t >> 6, lane = t & 63;
    const int wr = wid >> 1, wc = wid & 1;
    const int c = lane & 15, g = lane >> 4;

    __shared__ ushort ldsA[128 * 64];
    __shared__ ushort ldsB[128 * 64];

    const ushort* Ag = cat_bf + (size_t)m0 * ND;
    const ushort* Bg = WoT_bf + (size_t)n0 * ND;

    f32x4 acc[4][4];
    #pragma unroll
    for (int m = 0; m < 4; ++m)
        #pragma unroll
        for (int n = 0; n < 4; ++n)
            acc[m][n] = (f32x4){0.f, 0.f, 0.f, 0.f};

    for (int k0 = 0; k0 < ND; k0 += 64) {
        __syncthreads();
        #pragma unroll
        for (int call = 0; call < 4; ++call) {
            const int chb = wid * 256 + call * 64;
            const int ch = chb + lane;
            const int row = ch >> 3, c16 = ch & 7;
            gld_lds16(Ag + (size_t)row * ND + k0 + c16 * 8, ldsA + (size_t)ch * 8);
            gld_lds16(Bg + (size_t)row * ND + k0 + c16 * 8, ldsB + (size_t)ch * 8);
        }
        __syncthreads();
        #pragma unroll
        for (int kc = 0; kc < 2; ++kc) {
            bf16x8 af[4], bfr[4];
            #pragma unroll
            for (int m = 0; m < 4; ++m)
                af[m] = *(const bf16x8*)(ldsA + (wr*64 + m*16 + c) * 64 + kc*32 + g*8);
            #pragma unroll
            for (int n = 0; n < 4; ++n)
                bfr[n] = *(const bf16x8*)(ldsB + (wc*64 + n*16 + c) * 64 + kc*32 + g*8);
            #pragma unroll
            for (int m = 0; m < 4; ++m)
                #pragma unroll
                for (int n = 0; n < 4; ++n)
                    acc[m][n] = __builtin_amdgcn_mfma_f32_16x16x32_bf16(af[m], bfr[n], acc[m][n], 0, 0, 0);
        }
    }

    #pragma unroll
    for (int m = 0; m < 4; ++m) {
        const int gr0 = m0 + wr*64 + m*16 + g*4;
        #pragma unroll
        for (int n = 0; n < 4; ++n) {
            const int gc = n0 + wc*64 + n*16 + c;
            const float bv_ = bo[gc];
            #pragma unroll
            for (int j = 0; j < 4; ++j)
                out[(size_t)(gr0 + j) * ND + gc] = acc[m][n][j] + bv_;
        }
    }
}

extern "C" void kernel_launch(void* const* d_in, const int* in_sizes, int n_in,
                              void* d_out, int out_size, void* d_ws, size_t ws_size,
                              hipStream_t stream) {
    const float* query = (const float*)d_in[0];
    const float* key_  = (const float*)d_in[1];
    const float* value = (const float*)d_in[2];
    const float* Wq = (const float*)d_in[3];
    const float* bq = (const float*)d_in[4];
    const float* Wk = (const float*)d_in[5];
    const float* bk = (const float*)d_in[6];
    const float* Wv = (const float*)d_in[7];
    const float* bv = (const float*)d_in[8];
    const float* Wo = (const float*)d_in[9];
    const float* bo = (const float*)d_in[10];
    float* out = (float*)d_out;

    const size_t per = (size_t)NB * NH * NS * DH;   // 4.19M
    const size_t xsz = (size_t)MROWS * ND;          // 4.19M

    ushort* X_bf   = (ushort*)d_ws;                 // 3*xsz
    ushort* qkv_bf = X_bf + 3 * xsz;                // 3*per  (q | k | v)
    ushort* vT_bf  = qkv_bf + 3 * per;              // per
    ushort* WT_bf  = vT_bf + per;                   // 3*1024*1024
    ushort* WoT_bf = WT_bf + (size_t)3 * ND * NCOLS;// 1024*1024
    ushort* cat_bf = X_bf;                          // alias: X dead after gemm_qkv

    convert_x<<<2048, 256, 0, stream>>>(query, key_, value, X_bf);
    repack_w<<<dim3(16, 16, 3), 256, 0, stream>>>(Wq, Wk, Wv, WT_bf);
    repack_wo<<<dim3(16, 16), 256, 0, stream>>>(Wo, WoT_bf);

    gemm_qkv<<<dim3(32, 8, 3), 256, 0, stream>>>(X_bf, WT_bf, bq, bk, bv, qkv_bf);
    v_transpose<<<dim3(8, 32), 256, 0, stream>>>(qkv_bf + 2 * per, vT_bf);

    attn_kernel<<<dim3(32, 32), 256, 0, stream>>>(qkv_bf, qkv_bf + per, vT_bf, cat_bf);

    gemm_out<<<dim3(32, 8), 256, 0, stream>>>(cat_bf, WoT_bf, bo, out);
}

// Round 4
// 281.092 us; speedup vs baseline: 8.4652x; 1.0951x over previous
//
#include <hip/hip_runtime.h>
#include <math.h>

#define NB 2
#define NS 2048
#define ND 1024
#define NH 16
#define DH 64
#define MROWS (NB*NS)     // 4096
#define NCOLS (NH*DH)     // 1024

typedef __attribute__((ext_vector_type(8))) short bf16x8;
typedef __attribute__((ext_vector_type(4))) float f32x4;
typedef __attribute__((ext_vector_type(4))) unsigned short ushort4t;
typedef __attribute__((ext_vector_type(8))) unsigned short ushort8t;
typedef unsigned short ushort;

static __device__ __forceinline__ ushort f2bf(float f) {
    union { float f; unsigned u; } v; v.f = f;
    unsigned r = (v.u + 0x7FFFu + ((v.u >> 16) & 1u)) >> 16;
    return (ushort)r;
}

static __device__ __forceinline__ void gld_lds16(const void* g, void* l) {
    __builtin_amdgcn_global_load_lds(
        (const __attribute__((address_space(1))) void*)g,
        (__attribute__((address_space(3))) void*)l, 16, 0, 0);
}

// ---------------- prep: X (q,k,v inputs) fp32 -> bf16 ----------------
__global__ __launch_bounds__(256) void convert_x(
    const float* __restrict__ q, const float* __restrict__ k,
    const float* __restrict__ v, ushort* __restrict__ X_bf)
{
    const size_t n1 = (size_t)MROWS * ND;
    const size_t off = ((size_t)blockIdx.x * 256 + threadIdx.x) * 8;
    const float* srcs[3] = {q, k, v};
    #pragma unroll
    for (int p = 0; p < 3; ++p) {
        float4 a = *(const float4*)(srcs[p] + off);
        float4 b = *(const float4*)(srcs[p] + off + 4);
        ushort8t w;
        w[0]=f2bf(a.x); w[1]=f2bf(a.y); w[2]=f2bf(a.z); w[3]=f2bf(a.w);
        w[4]=f2bf(b.x); w[5]=f2bf(b.y); w[6]=f2bf(b.z); w[7]=f2bf(b.w);
        *(ushort8t*)(X_bf + (size_t)p * n1 + off) = w;
    }
}

// ---------------- prep: Wq/Wk/Wv [H][D][64] -> bf16 W^T [p][h*64+e][d] ----------------
__global__ __launch_bounds__(256) void repack_w(
    const float* __restrict__ Wq, const float* __restrict__ Wk,
    const float* __restrict__ Wv, ushort* __restrict__ WT_bf)
{
    const int p = blockIdx.z;
    const float* W = (p == 0) ? Wq : (p == 1) ? Wk : Wv;
    const int h = blockIdx.y, d0 = blockIdx.x * 64;
    __shared__ float tile[64][65];
    const int t = threadIdx.x;
    {
        const int i = t >> 2, e0 = (t & 3) * 16;
        const float* src = W + ((size_t)h * ND + d0 + i) * DH + e0;
        #pragma unroll
        for (int u = 0; u < 4; ++u) {
            float4 v4 = ((const float4*)src)[u];
            tile[i][e0 + u*4 + 0] = v4.x; tile[i][e0 + u*4 + 1] = v4.y;
            tile[i][e0 + u*4 + 2] = v4.z; tile[i][e0 + u*4 + 3] = v4.w;
        }
    }
    __syncthreads();
    {
        const int e = t >> 2, dc = (t & 3) * 16;
        ushort* dst = WT_bf + ((size_t)p * NCOLS + h * 64 + e) * ND + d0 + dc;
        ushort8t w0, w1;
        #pragma unroll
        for (int u = 0; u < 8; ++u) { w0[u] = f2bf(tile[dc+u][e]); w1[u] = f2bf(tile[dc+8+u][e]); }
        *(ushort8t*)dst = w0;
        *(ushort8t*)(dst + 8) = w1;
    }
}

// ---------------- prep: Wo [1024][1024] -> bf16 Wo^T [c][f] ----------------
__global__ __launch_bounds__(256) void repack_wo(
    const float* __restrict__ Wo, ushort* __restrict__ WoT_bf)
{
    const int f0 = blockIdx.x * 64, c0 = blockIdx.y * 64;
    __shared__ float tile[64][65];
    const int t = threadIdx.x;
    {
        const int i = t >> 2, j0 = (t & 3) * 16;
        const float* src = Wo + (size_t)(f0 + i) * ND + c0 + j0;
        #pragma unroll
        for (int u = 0; u < 4; ++u) {
            float4 v4 = ((const float4*)src)[u];
            tile[i][j0 + u*4 + 0] = v4.x; tile[i][j0 + u*4 + 1] = v4.y;
            tile[i][j0 + u*4 + 2] = v4.z; tile[i][j0 + u*4 + 3] = v4.w;
        }
    }
    __syncthreads();
    {
        const int cl = t >> 2, fc = (t & 3) * 16;
        ushort* dst = WoT_bf + (size_t)(c0 + cl) * ND + f0 + fc;
        ushort8t w0, w1;
        #pragma unroll
        for (int u = 0; u < 8; ++u) { w0[u] = f2bf(tile[fc+u][cl]); w1[u] = f2bf(tile[fc+8+u][cl]); }
        *(ushort8t*)dst = w0;
        *(ushort8t*)(dst + 8) = w1;
    }
}

// ---------------- Kernel: QKV projection GEMM, bf16 MFMA ----------------
__global__ __launch_bounds__(256) void gemm_qkv(
    const ushort* __restrict__ X_bf, const ushort* __restrict__ WT_bf,
    const float* __restrict__ bq, const float* __restrict__ bk,
    const float* __restrict__ bv, ushort* __restrict__ qkv_bf)
{
    const int p = blockIdx.z;
    const float* bias = (p == 0) ? bq : (p == 1) ? bk : bv;
    const float scale = (p == 0) ? 0.125f : 1.0f;
    const int m0 = blockIdx.x * 128, n0 = blockIdx.y * 128;
    const int t = threadIdx.x, wid = t >> 6, lane = t & 63;
    const int wr = wid >> 1, wc = wid & 1;
    const int c = lane & 15, g = lane >> 4;

    __shared__ ushort ldsA[128 * 64];
    __shared__ ushort ldsB[128 * 64];

    const ushort* Ag = X_bf + (size_t)p * MROWS * ND + (size_t)m0 * ND;
    const ushort* Bg = WT_bf + (size_t)p * NCOLS * ND + (size_t)n0 * ND;

    f32x4 acc[4][4];
    #pragma unroll
    for (int m = 0; m < 4; ++m)
        #pragma unroll
        for (int n = 0; n < 4; ++n)
            acc[m][n] = (f32x4){0.f, 0.f, 0.f, 0.f};

    for (int k0 = 0; k0 < ND; k0 += 64) {
        __syncthreads();
        #pragma unroll
        for (int call = 0; call < 4; ++call) {
            const int chb = wid * 256 + call * 64;
            const int ch = chb + lane;
            const int row = ch >> 3, c16 = ch & 7;
            gld_lds16(Ag + (size_t)row * ND + k0 + c16 * 8, ldsA + (size_t)ch * 8);
            gld_lds16(Bg + (size_t)row * ND + k0 + c16 * 8, ldsB + (size_t)ch * 8);
        }
        __syncthreads();
        #pragma unroll
        for (int kc = 0; kc < 2; ++kc) {
            bf16x8 af[4], bfr[4];
            #pragma unroll
            for (int m = 0; m < 4; ++m)
                af[m] = *(const bf16x8*)(ldsA + (wr*64 + m*16 + c) * 64 + kc*32 + g*8);
            #pragma unroll
            for (int n = 0; n < 4; ++n)
                bfr[n] = *(const bf16x8*)(ldsB + (wc*64 + n*16 + c) * 64 + kc*32 + g*8);
            #pragma unroll
            for (int m = 0; m < 4; ++m)
                #pragma unroll
                for (int n = 0; n < 4; ++n)
                    acc[m][n] = __builtin_amdgcn_mfma_f32_16x16x32_bf16(af[m], bfr[n], acc[m][n], 0, 0, 0);
        }
    }

    ushort* dst = qkv_bf + (size_t)p * ((size_t)NB * NH * NS * DH);
    #pragma unroll
    for (int m = 0; m < 4; ++m) {
        const int gr0 = m0 + wr*64 + m*16 + g*4;
        #pragma unroll
        for (int n = 0; n < 4; ++n) {
            const int gc = n0 + wc*64 + n*16 + c;
            const int h = gc >> 6, e = gc & 63;
            const float bv_ = bias[gc];
            #pragma unroll
            for (int j = 0; j < 4; ++j) {
                const int r = gr0 + j;
                const int b = r >> 11, s = r & (NS - 1);
                dst[(((size_t)b * NH + h) * NS + s) * DH + e] = f2bf((acc[m][n][j] + bv_) * scale);
            }
        }
    }
}

// ---------------- V transpose: [bh][s][64] -> [bh][e][S] ----------------
__global__ __launch_bounds__(256) void v_transpose(
    const ushort* __restrict__ v_bf, ushort* __restrict__ vT_bf)
{
    const int bh = blockIdx.y, s0 = blockIdx.x * 256;
    __shared__ ushort tile[256][72];
    const int t = threadIdx.x;
    const ushort* src = v_bf + ((size_t)bh * NS + s0) * DH;
    #pragma unroll
    for (int u = 0; u < 8; ++u) {
        const int idx = u * 256 + t;
        const int row = idx >> 3, cc = (idx & 7) * 8;
        *(ushort8t*)&tile[row][cc] = *(const ushort8t*)(src + (size_t)row * DH + cc);
    }
    __syncthreads();
    const int e = t >> 2, sc = (t & 3) * 64;
    ushort* dst = vT_bf + ((size_t)bh * DH + e) * NS + s0 + sc;
    #pragma unroll
    for (int u = 0; u < 8; ++u) {
        ushort8t w;
        #pragma unroll
        for (int x = 0; x < 8; ++x) w[x] = tile[sc + u*8 + x][e];
        *(ushort8t*)(dst + u * 8) = w;
    }
}

// ---------------- Kernel: flash attention, bf16 MFMA ----------------
// grid: (NS/64, NB*NH), block: 256 (4 waves, 16 q-rows each)
// LDS: K dbuf 2x8K | VT dbuf 2x8K | Ps 4x2K = 40960 B -> 4 blocks/CU
__global__ __launch_bounds__(256) void attn_kernel(
    const ushort* __restrict__ q_bf, const ushort* __restrict__ k_bf,
    const ushort* __restrict__ vT_bf, ushort* __restrict__ cat_bf)
{
    __shared__ __attribute__((aligned(16))) char smem[40960];
    const int t = threadIdx.x;
    const int wid = t >> 6, lane = t & 63;
    const int g = lane >> 4, c = lane & 15;
    const int bh = blockIdx.y;
    const int qrow0 = blockIdx.x * 64 + wid * 16;

    bf16x8 qf[2];
    {
        const char* qp = (const char*)(q_bf + ((size_t)bh * NS + qrow0 + c) * DH);
        qf[0] = *(const bf16x8*)(qp + g * 16);
        qf[1] = *(const bf16x8*)(qp + 64 + g * 16);
    }

    f32x4 o_acc[4];
    const f32x4 zero = {0.f, 0.f, 0.f, 0.f};
    #pragma unroll
    for (int n = 0; n < 4; ++n) o_acc[n] = zero;
    float m[4], lsum[4];
    #pragma unroll
    for (int r = 0; r < 4; ++r) { m[r] = -INFINITY; lsum[r] = 0.f; }

    const char* kg = (const char*)(k_bf + (size_t)bh * NS * DH);
    const char* vg = (const char*)(vT_bf + (size_t)bh * DH * NS);

    // per-thread staging geometry (2 chunks of 16B for K and for V)
    const int ch0 = t * 2;
    const int row0 = ch0 >> 3, c16a = ch0 & 7;
    const int row1 = (ch0 + 1) >> 3, c16b = (ch0 + 1) & 7;
    const int swz0 = (c16a * 16) ^ ((row0 & 7) << 4);
    const int swz1 = (c16b * 16) ^ ((row1 & 7) << 4);

    ushort8t kr0, kr1, vr0, vr1;

    #define ATTN_LOAD(JT) do { \
        kr0 = *(const ushort8t*)(kg + (size_t)((JT) + row0) * 128 + c16a * 16); \
        kr1 = *(const ushort8t*)(kg + (size_t)((JT) + row1) * 128 + c16b * 16); \
        vr0 = *(const ushort8t*)(vg + (size_t)row0 * (NS*2) + (size_t)((JT) + c16a*8) * 2); \
        vr1 = *(const ushort8t*)(vg + (size_t)row1 * (NS*2) + (size_t)((JT) + c16b*8) * 2); \
    } while (0)

    #define ATTN_STORE(BUF) do { \
        char* Kd = smem + (BUF) * 8192; \
        char* Vd = smem + 16384 + (BUF) * 8192; \
        *(ushort8t*)(Kd + row0 * 128 + swz0) = kr0; \
        *(ushort8t*)(Kd + row1 * 128 + swz1) = kr1; \
        *(ushort8t*)(Vd + row0 * 128 + swz0) = vr0; \
        *(ushort8t*)(Vd + row1 * 128 + swz1) = vr1; \
    } while (0)

    ATTN_LOAD(0);
    ATTN_STORE(0);
    __syncthreads();
    int cur = 0;
    char* Ps = smem + 32768 + wid * 2048;

    for (int jt = 0; jt < NS; jt += 64) {
        // T14: issue next tile's global loads; they stay in flight during compute
        ATTN_LOAD((jt + 64) & (NS - 1));

        const char* Ks  = smem + cur * 8192;
        const char* VTs = smem + 16384 + cur * 8192;

        // QK^T
        f32x4 s_acc[4];
        #pragma unroll
        for (int n = 0; n < 4; ++n) s_acc[n] = zero;
        __builtin_amdgcn_s_setprio(1);
        #pragma unroll
        for (int n = 0; n < 4; ++n) {
            const int key = n * 16 + c;
            #pragma unroll
            for (int kc = 0; kc < 2; ++kc) {
                bf16x8 kf = *(const bf16x8*)(Ks + key * 128 + ((kc * 64 + g * 16) ^ ((key & 7) << 4)));
                s_acc[n] = __builtin_amdgcn_mfma_f32_16x16x32_bf16(qf[kc], kf, s_acc[n], 0, 0, 0);
            }
        }
        __builtin_amdgcn_s_setprio(0);

        // online softmax with defer-max (T13): lane-partial max check via __all;
        // full shfl reduce only when the running max must move (≈ first tile only).
        float pv[4][4];
        #pragma unroll
        for (int r = 0; r < 4; ++r) {
            float tm = fmaxf(fmaxf(s_acc[0][r], s_acc[1][r]), fmaxf(s_acc[2][r], s_acc[3][r]));
            if (!__all(tm <= m[r] + 8.f)) {
                tm = fmaxf(tm, __shfl_xor(tm, 1));
                tm = fmaxf(tm, __shfl_xor(tm, 2));
                tm = fmaxf(tm, __shfl_xor(tm, 4));
                tm = fmaxf(tm, __shfl_xor(tm, 8));
                const float mnew = fmaxf(m[r], tm);
                const float sc = __expf(m[r] - mnew);
                lsum[r] *= sc;
                o_acc[0][r] *= sc; o_acc[1][r] *= sc;
                o_acc[2][r] *= sc; o_acc[3][r] *= sc;
                m[r] = mnew;
            }
            float rs = 0.f;
            #pragma unroll
            for (int n = 0; n < 4; ++n) {
                float pj = __expf(s_acc[n][r] - m[r]);
                pv[n][r] = pj;
                rs += pj;
            }
            lsum[r] += rs;   // lane-partial; reduced once at the end
        }

        // P -> per-wave LDS tile (bf16, swizzled), wave-synchronous
        #pragma unroll
        for (int n = 0; n < 4; ++n) {
            #pragma unroll
            for (int r = 0; r < 4; ++r) {
                const int q = g * 4 + r;
                *(ushort*)(Ps + q * 128 + ((n * 32 + c * 2) ^ ((q & 7) << 4))) = f2bf(pv[n][r]);
            }
        }

        // PV
        __builtin_amdgcn_s_setprio(1);
        #pragma unroll
        for (int kc = 0; kc < 2; ++kc) {
            bf16x8 pa = *(const bf16x8*)(Ps + c * 128 + ((kc * 64 + g * 16) ^ ((c & 7) << 4)));
            #pragma unroll
            for (int n = 0; n < 4; ++n) {
                const int e = n * 16 + c;
                bf16x8 vf = *(const bf16x8*)(VTs + e * 128 + ((kc * 64 + g * 16) ^ ((e & 7) << 4)));
                o_acc[n] = __builtin_amdgcn_mfma_f32_16x16x32_bf16(pa, vf, o_acc[n], 0, 0, 0);
            }
        }
        __builtin_amdgcn_s_setprio(0);

        // write next tile into the other buffer (compiler inserts vmcnt wait)
        ATTN_STORE(cur ^ 1);
        __syncthreads();
        cur ^= 1;
    }

    // final cross-lane lsum reduce (16-lane groups)
    #pragma unroll
    for (int r = 0; r < 4; ++r) {
        float rs = lsum[r];
        rs += __shfl_xor(rs, 1);
        rs += __shfl_xor(rs, 2);
        rs += __shfl_xor(rs, 4);
        rs += __shfl_xor(rs, 8);
        lsum[r] = rs;
    }

    // write bf16 into cat layout [b*S + s][h*64 + e]
    const int b = bh >> 4, hh = bh & 15;
    ushort* op = cat_bf + (size_t)b * NS * NCOLS + hh * DH;
    #pragma unroll
    for (int r = 0; r < 4; ++r) {
        const float inv = 1.0f / lsum[r];
        const int srow = qrow0 + g * 4 + r;
        #pragma unroll
        for (int n = 0; n < 4; ++n)
            op[(size_t)srow * NCOLS + n * 16 + c] = f2bf(o_acc[n][r] * inv);
    }
    #undef ATTN_LOAD
    #undef ATTN_STORE
}

// ---------------- Kernel: output GEMM, bf16 MFMA, fp32 out ----------------
__global__ __launch_bounds__(256) void gemm_out(
    const ushort* __restrict__ cat_bf, const ushort* __restrict__ WoT_bf,
    const float* __restrict__ bo, float* __restrict__ out)
{
    const int m0 = blockIdx.x * 128, n0 = blockIdx.y * 128;
    const int t = threadIdx.x, wid = t >> 6, lane = t & 63;
    const int wr = wid >> 1, wc = wid & 1;
    const int c = lane & 15, g = lane >> 4;

    __shared__ ushort ldsA[128 * 64];
    __shared__ ushort ldsB[128 * 64];

    const ushort* Ag = cat_bf + (size_t)m0 * ND;
    const ushort* Bg = WoT_bf + (size_t)n0 * ND;

    f32x4 acc[4][4];
    #pragma unroll
    for (int m = 0; m < 4; ++m)
        #pragma unroll
        for (int n = 0; n < 4; ++n)
            acc[m][n] = (f32x4){0.f, 0.f, 0.f, 0.f};

    for (int k0 = 0; k0 < ND; k0 += 64) {
        __syncthreads();
        #pragma unroll
        for (int call = 0; call < 4; ++call) {
            const int chb = wid * 256 + call * 64;
            const int ch = chb + lane;
            const int row = ch >> 3, c16 = ch & 7;
            gld_lds16(Ag + (size_t)row * ND + k0 + c16 * 8, ldsA + (size_t)ch * 8);
            gld_lds16(Bg + (size_t)row * ND + k0 + c16 * 8, ldsB + (size_t)ch * 8);
        }
        __syncthreads();
        #pragma unroll
        for (int kc = 0; kc < 2; ++kc) {
            bf16x8 af[4], bfr[4];
            #pragma unroll
            for (int m = 0; m < 4; ++m)
                af[m] = *(const bf16x8*)(ldsA + (wr*64 + m*16 + c) * 64 + kc*32 + g*8);
            #pragma unroll
            for (int n = 0; n < 4; ++n)
                bfr[n] = *(const bf16x8*)(ldsB + (wc*64 + n*16 + c) * 64 + kc*32 + g*8);
            #pragma unroll
            for (int m = 0; m < 4; ++m)
                #pragma unroll
                for (int n = 0; n < 4; ++n)
                    acc[m][n] = __builtin_amdgcn_mfma_f32_16x16x32_bf16(af[m], bfr[n], acc[m][n], 0, 0, 0);
        }
    }

    #pragma unroll
    for (int m = 0; m < 4; ++m) {
        const int gr0 = m0 + wr*64 + m*16 + g*4;
        #pragma unroll
        for (int n = 0; n < 4; ++n) {
            const int gc = n0 + wc*64 + n*16 + c;
            const float bv_ = bo[gc];
            #pragma unroll
            for (int j = 0; j < 4; ++j)
                out[(size_t)(gr0 + j) * ND + gc] = acc[m][n][j] + bv_;
        }
    }
}

extern "C" void kernel_launch(void* const* d_in, const int* in_sizes, int n_in,
                              void* d_out, int out_size, void* d_ws, size_t ws_size,
                              hipStream_t stream) {
    const float* query = (const float*)d_in[0];
    const float* key_  = (const float*)d_in[1];
    const float* value = (const float*)d_in[2];
    const float* Wq = (const float*)d_in[3];
    const float* bq = (const float*)d_in[4];
    const float* Wk = (const float*)d_in[5];
    const float* bk = (const float*)d_in[6];
    const float* Wv = (const float*)d_in[7];
    const float* bv = (const float*)d_in[8];
    const float* Wo = (const float*)d_in[9];
    const float* bo = (const float*)d_in[10];
    float* out = (float*)d_out;

    const size_t per = (size_t)NB * NH * NS * DH;   // 4.19M
    const size_t xsz = (size_t)MROWS * ND;          // 4.19M

    ushort* X_bf   = (ushort*)d_ws;                 // 3*xsz
    ushort* qkv_bf = X_bf + 3 * xsz;                // 3*per  (q | k | v)
    ushort* vT_bf  = qkv_bf + 3 * per;              // per
    ushort* WT_bf  = vT_bf + per;                   // 3*1024*1024
    ushort* WoT_bf = WT_bf + (size_t)3 * ND * NCOLS;// 1024*1024
    ushort* cat_bf = X_bf;                          // alias: X dead after gemm_qkv

    convert_x<<<2048, 256, 0, stream>>>(query, key_, value, X_bf);
    repack_w<<<dim3(16, 16, 3), 256, 0, stream>>>(Wq, Wk, Wv, WT_bf);
    repack_wo<<<dim3(16, 16), 256, 0, stream>>>(Wo, WoT_bf);

    gemm_qkv<<<dim3(32, 8, 3), 256, 0, stream>>>(X_bf, WT_bf, bq, bk, bv, qkv_bf);
    v_transpose<<<dim3(8, 32), 256, 0, stream>>>(qkv_bf + 2 * per, vT_bf);

    attn_kernel<<<dim3(32, 32), 256, 0, stream>>>(qkv_bf, qkv_bf + per, vT_bf, cat_bf);

    gemm_out<<<dim3(32, 8), 256, 0, stream>>>(cat_bf, WoT_bf, bo, out);
}

// Round 6
// 276.138 us; speedup vs baseline: 8.6171x; 1.0179x over previous
//
#include <hip/hip_runtime.h>
#include <hip/hip_bf16.h>
#include <math.h>

#define NB 2
#define NS 2048
#define ND 1024
#define NH 16
#define DH 64
#define MROWS (NB*NS)     // 4096
#define NCOLS (NH*DH)     // 1024

typedef __attribute__((ext_vector_type(8))) short bf16x8;
typedef __attribute__((ext_vector_type(4))) float f32x4;
typedef __attribute__((ext_vector_type(4))) unsigned short ushort4t;
typedef __attribute__((ext_vector_type(8))) unsigned short ushort8t;
typedef unsigned short ushort;

extern "C" __device__ float __ocml_native_exp2_f32(float);
#define EXP2F(x) __ocml_native_exp2_f32(x)
#define LOG2E 1.44269504088896f

// HW bf16 convert (v_cvt_pk_bf16_f32 on gfx950) — 1 VALU op vs 4-op bit-twiddle
static __device__ __forceinline__ ushort f2bf(float f) {
    union { __hip_bfloat16 b; ushort u; } cv;
    cv.b = __hip_bfloat16(f);
    return cv.u;
}

static __device__ __forceinline__ void gld_lds16(const void* g, void* l) {
    __builtin_amdgcn_global_load_lds(
        (const __attribute__((address_space(1))) void*)g,
        (__attribute__((address_space(3))) void*)l, 16, 0, 0);
}

// ---------------- prep: X (q,k,v inputs) fp32 -> bf16 ----------------
__global__ __launch_bounds__(256) void convert_x(
    const float* __restrict__ q, const float* __restrict__ k,
    const float* __restrict__ v, ushort* __restrict__ X_bf)
{
    const size_t n1 = (size_t)MROWS * ND;
    const size_t off = ((size_t)blockIdx.x * 256 + threadIdx.x) * 8;
    const float* srcs[3] = {q, k, v};
    #pragma unroll
    for (int p = 0; p < 3; ++p) {
        float4 a = *(const float4*)(srcs[p] + off);
        float4 b = *(const float4*)(srcs[p] + off + 4);
        ushort8t w;
        w[0]=f2bf(a.x); w[1]=f2bf(a.y); w[2]=f2bf(a.z); w[3]=f2bf(a.w);
        w[4]=f2bf(b.x); w[5]=f2bf(b.y); w[6]=f2bf(b.z); w[7]=f2bf(b.w);
        *(ushort8t*)(X_bf + (size_t)p * n1 + off) = w;
    }
}

// ---------------- prep: Wq/Wk/Wv [H][D][64] -> bf16 W^T [p][h*64+e][d] ----------------
__global__ __launch_bounds__(256) void repack_w(
    const float* __restrict__ Wq, const float* __restrict__ Wk,
    const float* __restrict__ Wv, ushort* __restrict__ WT_bf)
{
    const int p = blockIdx.z;
    const float* W = (p == 0) ? Wq : (p == 1) ? Wk : Wv;
    const int h = blockIdx.y, d0 = blockIdx.x * 64;
    __shared__ float tile[64][65];
    const int t = threadIdx.x;
    {
        const int i = t >> 2, e0 = (t & 3) * 16;
        const float* src = W + ((size_t)h * ND + d0 + i) * DH + e0;
        #pragma unroll
        for (int u = 0; u < 4; ++u) {
            float4 v4 = ((const float4*)src)[u];
            tile[i][e0 + u*4 + 0] = v4.x; tile[i][e0 + u*4 + 1] = v4.y;
            tile[i][e0 + u*4 + 2] = v4.z; tile[i][e0 + u*4 + 3] = v4.w;
        }
    }
    __syncthreads();
    {
        const int e = t >> 2, dc = (t & 3) * 16;
        ushort* dst = WT_bf + ((size_t)p * NCOLS + h * 64 + e) * ND + d0 + dc;
        ushort8t w0, w1;
        #pragma unroll
        for (int u = 0; u < 8; ++u) { w0[u] = f2bf(tile[dc+u][e]); w1[u] = f2bf(tile[dc+8+u][e]); }
        *(ushort8t*)dst = w0;
        *(ushort8t*)(dst + 8) = w1;
    }
}

// ---------------- prep: Wo [1024][1024] -> bf16 Wo^T [c][f] ----------------
__global__ __launch_bounds__(256) void repack_wo(
    const float* __restrict__ Wo, ushort* __restrict__ WoT_bf)
{
    const int f0 = blockIdx.x * 64, c0 = blockIdx.y * 64;
    __shared__ float tile[64][65];
    const int t = threadIdx.x;
    {
        const int i = t >> 2, j0 = (t & 3) * 16;
        const float* src = Wo + (size_t)(f0 + i) * ND + c0 + j0;
        #pragma unroll
        for (int u = 0; u < 4; ++u) {
            float4 v4 = ((const float4*)src)[u];
            tile[i][j0 + u*4 + 0] = v4.x; tile[i][j0 + u*4 + 1] = v4.y;
            tile[i][j0 + u*4 + 2] = v4.z; tile[i][j0 + u*4 + 3] = v4.w;
        }
    }
    __syncthreads();
    {
        const int cl = t >> 2, fc = (t & 3) * 16;
        ushort* dst = WoT_bf + (size_t)(c0 + cl) * ND + f0 + fc;
        ushort8t w0, w1;
        #pragma unroll
        for (int u = 0; u < 8; ++u) { w0[u] = f2bf(tile[fc+u][cl]); w1[u] = f2bf(tile[fc+8+u][cl]); }
        *(ushort8t*)dst = w0;
        *(ushort8t*)(dst + 8) = w1;
    }
}

// ---------------- Kernel: QKV projection GEMM, bf16 MFMA ----------------
// Q output pre-scaled by (1/8)*log2(e) so attention softmax runs in exp2 domain.
__global__ __launch_bounds__(256) void gemm_qkv(
    const ushort* __restrict__ X_bf, const ushort* __restrict__ WT_bf,
    const float* __restrict__ bq, const float* __restrict__ bk,
    const float* __restrict__ bv, ushort* __restrict__ qkv_bf)
{
    const int p = blockIdx.z;
    const float* bias = (p == 0) ? bq : (p == 1) ? bk : bv;
    const float scale = (p == 0) ? 0.125f * LOG2E : 1.0f;
    const int m0 = blockIdx.x * 128, n0 = blockIdx.y * 128;
    const int t = threadIdx.x, wid = t >> 6, lane = t & 63;
    const int wr = wid >> 1, wc = wid & 1;
    const int c = lane & 15, g = lane >> 4;

    __shared__ ushort ldsA[128 * 64];
    __shared__ ushort ldsB[128 * 64];

    const ushort* Ag = X_bf + (size_t)p * MROWS * ND + (size_t)m0 * ND;
    const ushort* Bg = WT_bf + (size_t)p * NCOLS * ND + (size_t)n0 * ND;

    f32x4 acc[4][4];
    #pragma unroll
    for (int m = 0; m < 4; ++m)
        #pragma unroll
        for (int n = 0; n < 4; ++n)
            acc[m][n] = (f32x4){0.f, 0.f, 0.f, 0.f};

    for (int k0 = 0; k0 < ND; k0 += 64) {
        __syncthreads();
        #pragma unroll
        for (int call = 0; call < 4; ++call) {
            const int chb = wid * 256 + call * 64;
            const int ch = chb + lane;
            const int row = ch >> 3, c16 = ch & 7;
            gld_lds16(Ag + (size_t)row * ND + k0 + c16 * 8, ldsA + (size_t)ch * 8);
            gld_lds16(Bg + (size_t)row * ND + k0 + c16 * 8, ldsB + (size_t)ch * 8);
        }
        __syncthreads();
        #pragma unroll
        for (int kc = 0; kc < 2; ++kc) {
            bf16x8 af[4], bfr[4];
            #pragma unroll
            for (int m = 0; m < 4; ++m)
                af[m] = *(const bf16x8*)(ldsA + (wr*64 + m*16 + c) * 64 + kc*32 + g*8);
            #pragma unroll
            for (int n = 0; n < 4; ++n)
                bfr[n] = *(const bf16x8*)(ldsB + (wc*64 + n*16 + c) * 64 + kc*32 + g*8);
            #pragma unroll
            for (int m = 0; m < 4; ++m)
                #pragma unroll
                for (int n = 0; n < 4; ++n)
                    acc[m][n] = __builtin_amdgcn_mfma_f32_16x16x32_bf16(af[m], bfr[n], acc[m][n], 0, 0, 0);
        }
    }

    ushort* dst = qkv_bf + (size_t)p * ((size_t)NB * NH * NS * DH);
    #pragma unroll
    for (int m = 0; m < 4; ++m) {
        const int gr0 = m0 + wr*64 + m*16 + g*4;
        #pragma unroll
        for (int n = 0; n < 4; ++n) {
            const int gc = n0 + wc*64 + n*16 + c;
            const int h = gc >> 6, e = gc & 63;
            const float bv_ = bias[gc];
            #pragma unroll
            for (int j = 0; j < 4; ++j) {
                const int r = gr0 + j;
                const int b = r >> 11, s = r & (NS - 1);
                dst[(((size_t)b * NH + h) * NS + s) * DH + e] = f2bf((acc[m][n][j] + bv_) * scale);
            }
        }
    }
}

// ---------------- V transpose: [bh][s][64] -> [bh][e][S] ----------------
__global__ __launch_bounds__(256) void v_transpose(
    const ushort* __restrict__ v_bf, ushort* __restrict__ vT_bf)
{
    const int bh = blockIdx.y, s0 = blockIdx.x * 256;
    __shared__ ushort tile[256][72];
    const int t = threadIdx.x;
    const ushort* src = v_bf + ((size_t)bh * NS + s0) * DH;
    #pragma unroll
    for (int u = 0; u < 8; ++u) {
        const int idx = u * 256 + t;
        const int row = idx >> 3, cc = (idx & 7) * 8;
        *(ushort8t*)&tile[row][cc] = *(const ushort8t*)(src + (size_t)row * DH + cc);
    }
    __syncthreads();
    const int e = t >> 2, sc = (t & 3) * 64;
    ushort* dst = vT_bf + ((size_t)bh * DH + e) * NS + s0 + sc;
    #pragma unroll
    for (int u = 0; u < 8; ++u) {
        ushort8t w;
        #pragma unroll
        for (int x = 0; x < 8; ++x) w[x] = tile[sc + u*8 + x][e];
        *(ushort8t*)(dst + u * 8) = w;
    }
}

// ---------------- Kernel: flash attention, bf16 MFMA, exp2-domain softmax ----------------
// grid: (NS/64, NB*NH), block: 256 (4 waves, 16 q-rows each)
// LDS: K dbuf 2x8K | VT dbuf 2x8K | Ps 4x2K = 40960 B
__global__ __launch_bounds__(256) void attn_kernel(
    const ushort* __restrict__ q_bf, const ushort* __restrict__ k_bf,
    const ushort* __restrict__ vT_bf, ushort* __restrict__ cat_bf)
{
    __shared__ __attribute__((aligned(16))) char smem[40960];
    const int t = threadIdx.x;
    const int wid = t >> 6, lane = t & 63;
    const int g = lane >> 4, c = lane & 15;
    const int bh = blockIdx.y;
    const int qrow0 = blockIdx.x * 64 + wid * 16;

    bf16x8 qf[2];
    {
        const char* qp = (const char*)(q_bf + ((size_t)bh * NS + qrow0 + c) * DH);
        qf[0] = *(const bf16x8*)(qp + g * 16);
        qf[1] = *(const bf16x8*)(qp + 64 + g * 16);
    }

    f32x4 o_acc[4];
    const f32x4 zero = {0.f, 0.f, 0.f, 0.f};
    #pragma unroll
    for (int n = 0; n < 4; ++n) o_acc[n] = zero;
    float m[4], lsum[4];
    #pragma unroll
    for (int r = 0; r < 4; ++r) { m[r] = -INFINITY; lsum[r] = 0.f; }

    const char* kg = (const char*)(k_bf + (size_t)bh * NS * DH);
    const char* vg = (const char*)(vT_bf + (size_t)bh * DH * NS);

    const int ch0 = t * 2;
    const int row0 = ch0 >> 3, c16a = ch0 & 7;
    const int row1 = (ch0 + 1) >> 3, c16b = (ch0 + 1) & 7;
    const int swz0 = (c16a * 16) ^ ((row0 & 7) << 4);
    const int swz1 = (c16b * 16) ^ ((row1 & 7) << 4);

    ushort8t kr0, kr1, vr0, vr1;

    #define ATTN_LOAD(JT) do { \
        kr0 = *(const ushort8t*)(kg + (size_t)((JT) + row0) * 128 + c16a * 16); \
        kr1 = *(const ushort8t*)(kg + (size_t)((JT) + row1) * 128 + c16b * 16); \
        vr0 = *(const ushort8t*)(vg + (size_t)row0 * (NS*2) + (size_t)((JT) + c16a*8) * 2); \
        vr1 = *(const ushort8t*)(vg + (size_t)row1 * (NS*2) + (size_t)((JT) + c16b*8) * 2); \
    } while (0)

    #define ATTN_STORE(BUF) do { \
        char* Kd = smem + (BUF) * 8192; \
        char* Vd = smem + 16384 + (BUF) * 8192; \
        *(ushort8t*)(Kd + row0 * 128 + swz0) = kr0; \
        *(ushort8t*)(Kd + row1 * 128 + swz1) = kr1; \
        *(ushort8t*)(Vd + row0 * 128 + swz0) = vr0; \
        *(ushort8t*)(Vd + row1 * 128 + swz1) = vr1; \
    } while (0)

    ATTN_LOAD(0);
    ATTN_STORE(0);
    __syncthreads();
    int cur = 0;
    char* Ps = smem + 32768 + wid * 2048;

    for (int jt = 0; jt < NS; jt += 64) {
        ATTN_LOAD((jt + 64) & (NS - 1));

        const char* Ks  = smem + cur * 8192;
        const char* VTs = smem + 16384 + cur * 8192;

        // QK^T (scores already in log2 units: Q pre-scaled by 0.125*log2e)
        f32x4 s_acc[4];
        #pragma unroll
        for (int n = 0; n < 4; ++n) s_acc[n] = zero;
        __builtin_amdgcn_s_setprio(1);
        #pragma unroll
        for (int n = 0; n < 4; ++n) {
            const int key = n * 16 + c;
            #pragma unroll
            for (int kc = 0; kc < 2; ++kc) {
                bf16x8 kf = *(const bf16x8*)(Ks + key * 128 + ((kc * 64 + g * 16) ^ ((key & 7) << 4)));
                s_acc[n] = __builtin_amdgcn_mfma_f32_16x16x32_bf16(qf[kc], kf, s_acc[n], 0, 0, 0);
            }
        }
        __builtin_amdgcn_s_setprio(0);

        // online softmax, exp2 domain, defer-max (thr 11.5 log2 ≈ 8 nats)
        float pv[4][4];
        #pragma unroll
        for (int r = 0; r < 4; ++r) {
            float tm = fmaxf(fmaxf(s_acc[0][r], s_acc[1][r]), fmaxf(s_acc[2][r], s_acc[3][r]));
            if (!__all(tm <= m[r] + 11.5f)) {
                tm = fmaxf(tm, __shfl_xor(tm, 1));
                tm = fmaxf(tm, __shfl_xor(tm, 2));
                tm = fmaxf(tm, __shfl_xor(tm, 4));
                tm = fmaxf(tm, __shfl_xor(tm, 8));
                const float mnew = fmaxf(m[r], tm);
                const float sc = EXP2F(m[r] - mnew);
                lsum[r] *= sc;
                o_acc[0][r] *= sc; o_acc[1][r] *= sc;
                o_acc[2][r] *= sc; o_acc[3][r] *= sc;
                m[r] = mnew;
            }
            float rs = 0.f;
            #pragma unroll
            for (int n = 0; n < 4; ++n) {
                float pj = EXP2F(s_acc[n][r] - m[r]);
                pv[n][r] = pj;
                rs += pj;
            }
            lsum[r] += rs;
        }

        // P -> per-wave LDS tile (bf16 via HW cvt, swizzled), wave-synchronous
        #pragma unroll
        for (int n = 0; n < 4; ++n) {
            #pragma unroll
            for (int r = 0; r < 4; ++r) {
                const int q = g * 4 + r;
                *(ushort*)(Ps + q * 128 + ((n * 32 + c * 2) ^ ((q & 7) << 4))) = f2bf(pv[n][r]);
            }
        }

        // PV
        __builtin_amdgcn_s_setprio(1);
        #pragma unroll
        for (int kc = 0; kc < 2; ++kc) {
            bf16x8 pa = *(const bf16x8*)(Ps + c * 128 + ((kc * 64 + g * 16) ^ ((c & 7) << 4)));
            #pragma unroll
            for (int n = 0; n < 4; ++n) {
                const int e = n * 16 + c;
                bf16x8 vf = *(const bf16x8*)(VTs + e * 128 + ((kc * 64 + g * 16) ^ ((e & 7) << 4)));
                o_acc[n] = __builtin_amdgcn_mfma_f32_16x16x32_bf16(pa, vf, o_acc[n], 0, 0, 0);
            }
        }
        __builtin_amdgcn_s_setprio(0);

        ATTN_STORE(cur ^ 1);
        __syncthreads();
        cur ^= 1;
    }

    #pragma unroll
    for (int r = 0; r < 4; ++r) {
        float rs = lsum[r];
        rs += __shfl_xor(rs, 1);
        rs += __shfl_xor(rs, 2);
        rs += __shfl_xor(rs, 4);
        rs += __shfl_xor(rs, 8);
        lsum[r] = rs;
    }

    const int b = bh >> 4, hh = bh & 15;
    ushort* op = cat_bf + (size_t)b * NS * NCOLS + hh * DH;
    #pragma unroll
    for (int r = 0; r < 4; ++r) {
        const float inv = 1.0f / lsum[r];
        const int srow = qrow0 + g * 4 + r;
        #pragma unroll
        for (int n = 0; n < 4; ++n)
            op[(size_t)srow * NCOLS + n * 16 + c] = f2bf(o_acc[n][r] * inv);
    }
    #undef ATTN_LOAD
    #undef ATTN_STORE
}

// ---------------- Kernel: output GEMM, bf16 MFMA, fp32 out ----------------
__global__ __launch_bounds__(256) void gemm_out(
    const ushort* __restrict__ cat_bf, const ushort* __restrict__ WoT_bf,
    const float* __restrict__ bo, float* __restrict__ out)
{
    const int m0 = blockIdx.x * 128, n0 = blockIdx.y * 128;
    const int t = threadIdx.x, wid = t >> 6, lane = t & 63;
    const int wr = wid >> 1, wc = wid & 1;
    const int c = lane & 15, g = lane >> 4;

    __shared__ ushort ldsA[128 * 64];
    __shared__ ushort ldsB[128 * 64];

    const ushort* Ag = cat_bf + (size_t)m0 * ND;
    const ushort* Bg = WoT_bf + (size_t)n0 * ND;

    f32x4 acc[4][4];
    #pragma unroll
    for (int m = 0; m < 4; ++m)
        #pragma unroll
        for (int n = 0; n < 4; ++n)
            acc[m][n] = (f32x4){0.f, 0.f, 0.f, 0.f};

    for (int k0 = 0; k0 < ND; k0 += 64) {
        __syncthreads();
        #pragma unroll
        for (int call = 0; call < 4; ++call) {
            const int chb = wid * 256 + call * 64;
            const int ch = chb + lane;
            const int row = ch >> 3, c16 = ch & 7;
            gld_lds16(Ag + (size_t)row * ND + k0 + c16 * 8, ldsA + (size_t)ch * 8);
            gld_lds16(Bg + (size_t)row * ND + k0 + c16 * 8, ldsB + (size_t)ch * 8);
        }
        __syncthreads();
        #pragma unroll
        for (int kc = 0; kc < 2; ++kc) {
            bf16x8 af[4], bfr[4];
            #pragma unroll
            for (int m = 0; m < 4; ++m)
                af[m] = *(const bf16x8*)(ldsA + (wr*64 + m*16 + c) * 64 + kc*32 + g*8);
            #pragma unroll
            for (int n = 0; n < 4; ++n)
                bfr[n] = *(const bf16x8*)(ldsB + (wc*64 + n*16 + c) * 64 + kc*32 + g*8);
            #pragma unroll
            for (int m = 0; m < 4; ++m)
                #pragma unroll
                for (int n = 0; n < 4; ++n)
                    acc[m][n] = __builtin_amdgcn_mfma_f32_16x16x32_bf16(af[m], bfr[n], acc[m][n], 0, 0, 0);
        }
    }

    #pragma unroll
    for (int m = 0; m < 4; ++m) {
        const int gr0 = m0 + wr*64 + m*16 + g*4;
        #pragma unroll
        for (int n = 0; n < 4; ++n) {
            const int gc = n0 + wc*64 + n*16 + c;
            const float bv_ = bo[gc];
            #pragma unroll
            for (int j = 0; j < 4; ++j)
                out[(size_t)(gr0 + j) * ND + gc] = acc[m][n][j] + bv_;
        }
    }
}

extern "C" void kernel_launch(void* const* d_in, const int* in_sizes, int n_in,
                              void* d_out, int out_size, void* d_ws, size_t ws_size,
                              hipStream_t stream) {
    const float* query = (const float*)d_in[0];
    const float* key_  = (const float*)d_in[1];
    const float* value = (const float*)d_in[2];
    const float* Wq = (const float*)d_in[3];
    const float* bq = (const float*)d_in[4];
    const float* Wk = (const float*)d_in[5];
    const float* bk = (const float*)d_in[6];
    const float* Wv = (const float*)d_in[7];
    const float* bv = (const float*)d_in[8];
    const float* Wo = (const float*)d_in[9];
    const float* bo = (const float*)d_in[10];
    float* out = (float*)d_out;

    const size_t per = (size_t)NB * NH * NS * DH;   // 4.19M
    const size_t xsz = (size_t)MROWS * ND;          // 4.19M

    ushort* X_bf   = (ushort*)d_ws;                 // 3*xsz
    ushort* qkv_bf = X_bf + 3 * xsz;                // 3*per  (q | k | v)
    ushort* vT_bf  = qkv_bf + 3 * per;              // per
    ushort* WT_bf  = vT_bf + per;                   // 3*1024*1024
    ushort* WoT_bf = WT_bf + (size_t)3 * ND * NCOLS;// 1024*1024
    ushort* cat_bf = X_bf;                          // alias: X dead after gemm_qkv

    convert_x<<<2048, 256, 0, stream>>>(query, key_, value, X_bf);
    repack_w<<<dim3(16, 16, 3), 256, 0, stream>>>(Wq, Wk, Wv, WT_bf);
    repack_wo<<<dim3(16, 16), 256, 0, stream>>>(Wo, WoT_bf);

    gemm_qkv<<<dim3(32, 8, 3), 256, 0, stream>>>(X_bf, WT_bf, bq, bk, bv, qkv_bf);
    v_transpose<<<dim3(8, 32), 256, 0, stream>>>(qkv_bf + 2 * per, vT_bf);

    attn_kernel<<<dim3(32, 32), 256, 0, stream>>>(qkv_bf, qkv_bf + per, vT_bf, cat_bf);

    gemm_out<<<dim3(32, 8), 256, 0, stream>>>(cat_bf, WoT_bf, bo, out);
}

// Round 7
// 274.763 us; speedup vs baseline: 8.6602x; 1.0050x over previous
//
#include <hip/hip_runtime.h>
#include <hip/hip_bf16.h>
#include <math.h>

#define NB 2
#define NS 2048
#define ND 1024
#define NH 16
#define DH 64
#define MROWS (NB*NS)     // 4096
#define NCOLS (NH*DH)     // 1024

typedef __attribute__((ext_vector_type(8))) short bf16x8;
typedef __attribute__((ext_vector_type(4))) float f32x4;
typedef __attribute__((ext_vector_type(4))) unsigned short ushort4t;
typedef __attribute__((ext_vector_type(8))) unsigned short ushort8t;
typedef unsigned short ushort;

extern "C" __device__ float __ocml_native_exp2_f32(float);
#define EXP2F(x) __ocml_native_exp2_f32(x)
#define LOG2E 1.44269504088896f

// HW bf16 convert (v_cvt_pk_bf16_f32 on gfx950)
static __device__ __forceinline__ ushort f2bf(float f) {
    union { __hip_bfloat16 b; ushort u; } cv;
    cv.b = __hip_bfloat16(f);
    return cv.u;
}

static __device__ __forceinline__ void gld_lds16(const void* g, void* l) {
    __builtin_amdgcn_global_load_lds(
        (const __attribute__((address_space(1))) void*)g,
        (__attribute__((address_space(3))) void*)l, 16, 0, 0);
}

// ---------------- prep: X (q,k,v inputs) fp32 -> bf16 ----------------
__global__ __launch_bounds__(256) void convert_x(
    const float* __restrict__ q, const float* __restrict__ k,
    const float* __restrict__ v, ushort* __restrict__ X_bf)
{
    const size_t n1 = (size_t)MROWS * ND;
    const size_t off = ((size_t)blockIdx.x * 256 + threadIdx.x) * 8;
    const float* srcs[3] = {q, k, v};
    #pragma unroll
    for (int p = 0; p < 3; ++p) {
        float4 a = *(const float4*)(srcs[p] + off);
        float4 b = *(const float4*)(srcs[p] + off + 4);
        ushort8t w;
        w[0]=f2bf(a.x); w[1]=f2bf(a.y); w[2]=f2bf(a.z); w[3]=f2bf(a.w);
        w[4]=f2bf(b.x); w[5]=f2bf(b.y); w[6]=f2bf(b.z); w[7]=f2bf(b.w);
        *(ushort8t*)(X_bf + (size_t)p * n1 + off) = w;
    }
}

// ---------------- prep: Wq/Wk/Wv [H][D][64] -> bf16 W^T [p][h*64+e][d] ----------------
__global__ __launch_bounds__(256) void repack_w(
    const float* __restrict__ Wq, const float* __restrict__ Wk,
    const float* __restrict__ Wv, ushort* __restrict__ WT_bf)
{
    const int p = blockIdx.z;
    const float* W = (p == 0) ? Wq : (p == 1) ? Wk : Wv;
    const int h = blockIdx.y, d0 = blockIdx.x * 64;
    __shared__ float tile[64][65];
    const int t = threadIdx.x;
    {
        const int i = t >> 2, e0 = (t & 3) * 16;
        const float* src = W + ((size_t)h * ND + d0 + i) * DH + e0;
        #pragma unroll
        for (int u = 0; u < 4; ++u) {
            float4 v4 = ((const float4*)src)[u];
            tile[i][e0 + u*4 + 0] = v4.x; tile[i][e0 + u*4 + 1] = v4.y;
            tile[i][e0 + u*4 + 2] = v4.z; tile[i][e0 + u*4 + 3] = v4.w;
        }
    }
    __syncthreads();
    {
        const int e = t >> 2, dc = (t & 3) * 16;
        ushort* dst = WT_bf + ((size_t)p * NCOLS + h * 64 + e) * ND + d0 + dc;
        ushort8t w0, w1;
        #pragma unroll
        for (int u = 0; u < 8; ++u) { w0[u] = f2bf(tile[dc+u][e]); w1[u] = f2bf(tile[dc+8+u][e]); }
        *(ushort8t*)dst = w0;
        *(ushort8t*)(dst + 8) = w1;
    }
}

// ---------------- prep: Wo [1024][1024] -> bf16 Wo^T [c][f] ----------------
__global__ __launch_bounds__(256) void repack_wo(
    const float* __restrict__ Wo, ushort* __restrict__ WoT_bf)
{
    const int f0 = blockIdx.x * 64, c0 = blockIdx.y * 64;
    __shared__ float tile[64][65];
    const int t = threadIdx.x;
    {
        const int i = t >> 2, j0 = (t & 3) * 16;
        const float* src = Wo + (size_t)(f0 + i) * ND + c0 + j0;
        #pragma unroll
        for (int u = 0; u < 4; ++u) {
            float4 v4 = ((const float4*)src)[u];
            tile[i][j0 + u*4 + 0] = v4.x; tile[i][j0 + u*4 + 1] = v4.y;
            tile[i][j0 + u*4 + 2] = v4.z; tile[i][j0 + u*4 + 3] = v4.w;
        }
    }
    __syncthreads();
    {
        const int cl = t >> 2, fc = (t & 3) * 16;
        ushort* dst = WoT_bf + (size_t)(c0 + cl) * ND + f0 + fc;
        ushort8t w0, w1;
        #pragma unroll
        for (int u = 0; u < 8; ++u) { w0[u] = f2bf(tile[fc+u][cl]); w1[u] = f2bf(tile[fc+8+u][cl]); }
        *(ushort8t*)dst = w0;
        *(ushort8t*)(dst + 8) = w1;
    }
}

// ---------------- Kernel: QKV projection GEMM, bf16 MFMA ----------------
// Q output pre-scaled by (1/8)*log2(e) so attention softmax runs in exp2 domain.
__global__ __launch_bounds__(256) void gemm_qkv(
    const ushort* __restrict__ X_bf, const ushort* __restrict__ WT_bf,
    const float* __restrict__ bq, const float* __restrict__ bk,
    const float* __restrict__ bv, ushort* __restrict__ qkv_bf)
{
    const int p = blockIdx.z;
    const float* bias = (p == 0) ? bq : (p == 1) ? bk : bv;
    const float scale = (p == 0) ? 0.125f * LOG2E : 1.0f;
    const int m0 = blockIdx.x * 128, n0 = blockIdx.y * 128;
    const int t = threadIdx.x, wid = t >> 6, lane = t & 63;
    const int wr = wid >> 1, wc = wid & 1;
    const int c = lane & 15, g = lane >> 4;

    __shared__ ushort ldsA[128 * 64];
    __shared__ ushort ldsB[128 * 64];

    const ushort* Ag = X_bf + (size_t)p * MROWS * ND + (size_t)m0 * ND;
    const ushort* Bg = WT_bf + (size_t)p * NCOLS * ND + (size_t)n0 * ND;

    f32x4 acc[4][4];
    #pragma unroll
    for (int m = 0; m < 4; ++m)
        #pragma unroll
        for (int n = 0; n < 4; ++n)
            acc[m][n] = (f32x4){0.f, 0.f, 0.f, 0.f};

    for (int k0 = 0; k0 < ND; k0 += 64) {
        __syncthreads();
        #pragma unroll
        for (int call = 0; call < 4; ++call) {
            const int chb = wid * 256 + call * 64;
            const int ch = chb + lane;
            const int row = ch >> 3, c16 = ch & 7;
            gld_lds16(Ag + (size_t)row * ND + k0 + c16 * 8, ldsA + (size_t)ch * 8);
            gld_lds16(Bg + (size_t)row * ND + k0 + c16 * 8, ldsB + (size_t)ch * 8);
        }
        __syncthreads();
        #pragma unroll
        for (int kc = 0; kc < 2; ++kc) {
            bf16x8 af[4], bfr[4];
            #pragma unroll
            for (int m = 0; m < 4; ++m)
                af[m] = *(const bf16x8*)(ldsA + (wr*64 + m*16 + c) * 64 + kc*32 + g*8);
            #pragma unroll
            for (int n = 0; n < 4; ++n)
                bfr[n] = *(const bf16x8*)(ldsB + (wc*64 + n*16 + c) * 64 + kc*32 + g*8);
            #pragma unroll
            for (int m = 0; m < 4; ++m)
                #pragma unroll
                for (int n = 0; n < 4; ++n)
                    acc[m][n] = __builtin_amdgcn_mfma_f32_16x16x32_bf16(af[m], bfr[n], acc[m][n], 0, 0, 0);
        }
    }

    ushort* dst = qkv_bf + (size_t)p * ((size_t)NB * NH * NS * DH);
    #pragma unroll
    for (int m = 0; m < 4; ++m) {
        const int gr0 = m0 + wr*64 + m*16 + g*4;
        #pragma unroll
        for (int n = 0; n < 4; ++n) {
            const int gc = n0 + wc*64 + n*16 + c;
            const int h = gc >> 6, e = gc & 63;
            const float bv_ = bias[gc];
            #pragma unroll
            for (int j = 0; j < 4; ++j) {
                const int r = gr0 + j;
                const int b = r >> 11, s = r & (NS - 1);
                dst[(((size_t)b * NH + h) * NS + s) * DH + e] = f2bf((acc[m][n][j] + bv_) * scale);
            }
        }
    }
}

// ---------------- V transpose: [bh][s][64] -> [bh][e][S] ----------------
__global__ __launch_bounds__(256) void v_transpose(
    const ushort* __restrict__ v_bf, ushort* __restrict__ vT_bf)
{
    const int bh = blockIdx.y, s0 = blockIdx.x * 256;
    __shared__ ushort tile[256][72];
    const int t = threadIdx.x;
    const ushort* src = v_bf + ((size_t)bh * NS + s0) * DH;
    #pragma unroll
    for (int u = 0; u < 8; ++u) {
        const int idx = u * 256 + t;
        const int row = idx >> 3, cc = (idx & 7) * 8;
        *(ushort8t*)&tile[row][cc] = *(const ushort8t*)(src + (size_t)row * DH + cc);
    }
    __syncthreads();
    const int e = t >> 2, sc = (t & 3) * 64;
    ushort* dst = vT_bf + ((size_t)bh * DH + e) * NS + s0 + sc;
    #pragma unroll
    for (int u = 0; u < 8; ++u) {
        ushort8t w;
        #pragma unroll
        for (int x = 0; x < 8; ++x) w[x] = tile[sc + u*8 + x][e];
        *(ushort8t*)(dst + u * 8) = w;
    }
}

// ---------------- Kernel: flash attention, bf16 MFMA, 8 waves/block ----------------
// grid: 512 1D blocks, block: 512 (8 waves, 16 q-rows each = 128 q-rows/block)
// XCD-aware: all 16 q-blocks of a head map to one XCD (4 heads/XCD) for K/V L2 residency.
// LDS: K dbuf 2x8K | VT dbuf 2x8K | Ps 8x2K = 49152 B -> 2 blocks/CU, 16 waves/CU
__global__ __launch_bounds__(512) void attn_kernel(
    const ushort* __restrict__ q_bf, const ushort* __restrict__ k_bf,
    const ushort* __restrict__ vT_bf, ushort* __restrict__ cat_bf)
{
    __shared__ __attribute__((aligned(16))) char smem[49152];
    const int t = threadIdx.x;
    const int wid = t >> 6, lane = t & 63;
    const int g = lane >> 4, c = lane & 15;

    // XCD-aware block -> (bh, qx): dispatch round-robins linear id over 8 XCDs
    const int linear = blockIdx.x;          // 0..511
    const int xcd = linear & 7;
    const int idx = linear >> 3;            // 0..63
    const int bh = xcd * 4 + (idx >> 4);    // 4 heads per XCD
    const int qx = idx & 15;
    const int qrow0 = qx * 128 + wid * 16;

    bf16x8 qf[2];
    {
        const char* qp = (const char*)(q_bf + ((size_t)bh * NS + qrow0 + c) * DH);
        qf[0] = *(const bf16x8*)(qp + g * 16);
        qf[1] = *(const bf16x8*)(qp + 64 + g * 16);
    }

    f32x4 o_acc[4];
    const f32x4 zero = {0.f, 0.f, 0.f, 0.f};
    #pragma unroll
    for (int n = 0; n < 4; ++n) o_acc[n] = zero;
    float m[4], lsum[4];
    #pragma unroll
    for (int r = 0; r < 4; ++r) { m[r] = -INFINITY; lsum[r] = 0.f; }

    const char* kg = (const char*)(k_bf + (size_t)bh * NS * DH);
    const char* vg = (const char*)(vT_bf + (size_t)bh * DH * NS);

    // staging: each of 512 threads loads one 16B chunk of K and one of V
    const int row = t >> 3, c16 = t & 7;       // row 0..63, chunk 0..7
    const int swz = (c16 * 16) ^ ((row & 7) << 4);

    ushort8t kr, vr;

    #define ATTN_LOAD(JT) do { \
        kr = *(const ushort8t*)(kg + (size_t)((JT) + row) * 128 + c16 * 16); \
        vr = *(const ushort8t*)(vg + (size_t)row * (NS*2) + (size_t)((JT) + c16*8) * 2); \
    } while (0)

    #define ATTN_STORE(BUF) do { \
        *(ushort8t*)(smem + (BUF) * 8192 + row * 128 + swz) = kr; \
        *(ushort8t*)(smem + 16384 + (BUF) * 8192 + row * 128 + swz) = vr; \
    } while (0)

    ATTN_LOAD(0);
    ATTN_STORE(0);
    __syncthreads();
    int cur = 0;
    char* Ps = smem + 32768 + wid * 2048;

    for (int jt = 0; jt < NS; jt += 64) {
        ATTN_LOAD((jt + 64) & (NS - 1));

        const char* Ks  = smem + cur * 8192;
        const char* VTs = smem + 16384 + cur * 8192;

        // QK^T (scores already in log2 units: Q pre-scaled by 0.125*log2e)
        f32x4 s_acc[4];
        #pragma unroll
        for (int n = 0; n < 4; ++n) s_acc[n] = zero;
        __builtin_amdgcn_s_setprio(1);
        #pragma unroll
        for (int n = 0; n < 4; ++n) {
            const int key = n * 16 + c;
            #pragma unroll
            for (int kc = 0; kc < 2; ++kc) {
                bf16x8 kf = *(const bf16x8*)(Ks + key * 128 + ((kc * 64 + g * 16) ^ ((key & 7) << 4)));
                s_acc[n] = __builtin_amdgcn_mfma_f32_16x16x32_bf16(qf[kc], kf, s_acc[n], 0, 0, 0);
            }
        }
        __builtin_amdgcn_s_setprio(0);

        // online softmax, exp2 domain, defer-max (thr 11.5 log2 ~ 8 nats)
        float pv[4][4];
        #pragma unroll
        for (int r = 0; r < 4; ++r) {
            float tm = fmaxf(fmaxf(s_acc[0][r], s_acc[1][r]), fmaxf(s_acc[2][r], s_acc[3][r]));
            if (!__all(tm <= m[r] + 11.5f)) {
                tm = fmaxf(tm, __shfl_xor(tm, 1));
                tm = fmaxf(tm, __shfl_xor(tm, 2));
                tm = fmaxf(tm, __shfl_xor(tm, 4));
                tm = fmaxf(tm, __shfl_xor(tm, 8));
                const float mnew = fmaxf(m[r], tm);
                const float sc = EXP2F(m[r] - mnew);
                lsum[r] *= sc;
                o_acc[0][r] *= sc; o_acc[1][r] *= sc;
                o_acc[2][r] *= sc; o_acc[3][r] *= sc;
                m[r] = mnew;
            }
            float rs = 0.f;
            #pragma unroll
            for (int n = 0; n < 4; ++n) {
                float pj = EXP2F(s_acc[n][r] - m[r]);
                pv[n][r] = pj;
                rs += pj;
            }
            lsum[r] += rs;
        }

        // P -> per-wave LDS tile (bf16, swizzled), wave-synchronous
        #pragma unroll
        for (int n = 0; n < 4; ++n) {
            #pragma unroll
            for (int r = 0; r < 4; ++r) {
                const int q = g * 4 + r;
                *(ushort*)(Ps + q * 128 + ((n * 32 + c * 2) ^ ((q & 7) << 4))) = f2bf(pv[n][r]);
            }
        }

        // PV
        __builtin_amdgcn_s_setprio(1);
        #pragma unroll
        for (int kc = 0; kc < 2; ++kc) {
            bf16x8 pa = *(const bf16x8*)(Ps + c * 128 + ((kc * 64 + g * 16) ^ ((c & 7) << 4)));
            #pragma unroll
            for (int n = 0; n < 4; ++n) {
                const int e = n * 16 + c;
                bf16x8 vf = *(const bf16x8*)(VTs + e * 128 + ((kc * 64 + g * 16) ^ ((e & 7) << 4)));
                o_acc[n] = __builtin_amdgcn_mfma_f32_16x16x32_bf16(pa, vf, o_acc[n], 0, 0, 0);
            }
        }
        __builtin_amdgcn_s_setprio(0);

        ATTN_STORE(cur ^ 1);
        __syncthreads();
        cur ^= 1;
    }

    #pragma unroll
    for (int r = 0; r < 4; ++r) {
        float rs = lsum[r];
        rs += __shfl_xor(rs, 1);
        rs += __shfl_xor(rs, 2);
        rs += __shfl_xor(rs, 4);
        rs += __shfl_xor(rs, 8);
        lsum[r] = rs;
    }

    const int b = bh >> 4, hh = bh & 15;
    ushort* op = cat_bf + (size_t)b * NS * NCOLS + hh * DH;
    #pragma unroll
    for (int r = 0; r < 4; ++r) {
        const float inv = 1.0f / lsum[r];
        const int srow = qrow0 + g * 4 + r;
        #pragma unroll
        for (int n = 0; n < 4; ++n)
            op[(size_t)srow * NCOLS + n * 16 + c] = f2bf(o_acc[n][r] * inv);
    }
    #undef ATTN_LOAD
    #undef ATTN_STORE
}

// ---------------- Kernel: output GEMM, bf16 MFMA, fp32 out ----------------
__global__ __launch_bounds__(256) void gemm_out(
    const ushort* __restrict__ cat_bf, const ushort* __restrict__ WoT_bf,
    const float* __restrict__ bo, float* __restrict__ out)
{
    const int m0 = blockIdx.x * 128, n0 = blockIdx.y * 128;
    const int t = threadIdx.x, wid = t >> 6, lane = t & 63;
    const int wr = wid >> 1, wc = wid & 1;
    const int c = lane & 15, g = lane >> 4;

    __shared__ ushort ldsA[128 * 64];
    __shared__ ushort ldsB[128 * 64];

    const ushort* Ag = cat_bf + (size_t)m0 * ND;
    const ushort* Bg = WoT_bf + (size_t)n0 * ND;

    f32x4 acc[4][4];
    #pragma unroll
    for (int m = 0; m < 4; ++m)
        #pragma unroll
        for (int n = 0; n < 4; ++n)
            acc[m][n] = (f32x4){0.f, 0.f, 0.f, 0.f};

    for (int k0 = 0; k0 < ND; k0 += 64) {
        __syncthreads();
        #pragma unroll
        for (int call = 0; call < 4; ++call) {
            const int chb = wid * 256 + call * 64;
            const int ch = chb + lane;
            const int row = ch >> 3, c16 = ch & 7;
            gld_lds16(Ag + (size_t)row * ND + k0 + c16 * 8, ldsA + (size_t)ch * 8);
            gld_lds16(Bg + (size_t)row * ND + k0 + c16 * 8, ldsB + (size_t)ch * 8);
        }
        __syncthreads();
        #pragma unroll
        for (int kc = 0; kc < 2; ++kc) {
            bf16x8 af[4], bfr[4];
            #pragma unroll
            for (int m = 0; m < 4; ++m)
                af[m] = *(const bf16x8*)(ldsA + (wr*64 + m*16 + c) * 64 + kc*32 + g*8);
            #pragma unroll
            for (int n = 0; n < 4; ++n)
                bfr[n] = *(const bf16x8*)(ldsB + (wc*64 + n*16 + c) * 64 + kc*32 + g*8);
            #pragma unroll
            for (int m = 0; m < 4; ++m)
                #pragma unroll
                for (int n = 0; n < 4; ++n)
                    acc[m][n] = __builtin_amdgcn_mfma_f32_16x16x32_bf16(af[m], bfr[n], acc[m][n], 0, 0, 0);
        }
    }

    #pragma unroll
    for (int m = 0; m < 4; ++m) {
        const int gr0 = m0 + wr*64 + m*16 + g*4;
        #pragma unroll
        for (int n = 0; n < 4; ++n) {
            const int gc = n0 + wc*64 + n*16 + c;
            const float bv_ = bo[gc];
            #pragma unroll
            for (int j = 0; j < 4; ++j)
                out[(size_t)(gr0 + j) * ND + gc] = acc[m][n][j] + bv_;
        }
    }
}

extern "C" void kernel_launch(void* const* d_in, const int* in_sizes, int n_in,
                              void* d_out, int out_size, void* d_ws, size_t ws_size,
                              hipStream_t stream) {
    const float* query = (const float*)d_in[0];
    const float* key_  = (const float*)d_in[1];
    const float* value = (const float*)d_in[2];
    const float* Wq = (const float*)d_in[3];
    const float* bq = (const float*)d_in[4];
    const float* Wk = (const float*)d_in[5];
    const float* bk = (const float*)d_in[6];
    const float* Wv = (const float*)d_in[7];
    const float* bv = (const float*)d_in[8];
    const float* Wo = (const float*)d_in[9];
    const float* bo = (const float*)d_in[10];
    float* out = (float*)d_out;

    const size_t per = (size_t)NB * NH * NS * DH;   // 4.19M
    const size_t xsz = (size_t)MROWS * ND;          // 4.19M

    ushort* X_bf   = (ushort*)d_ws;                 // 3*xsz
    ushort* qkv_bf = X_bf + 3 * xsz;                // 3*per  (q | k | v)
    ushort* vT_bf  = qkv_bf + 3 * per;              // per
    ushort* WT_bf  = vT_bf + per;                   // 3*1024*1024
    ushort* WoT_bf = WT_bf + (size_t)3 * ND * NCOLS;// 1024*1024
    ushort* cat_bf = X_bf;                          // alias: X dead after gemm_qkv

    convert_x<<<2048, 256, 0, stream>>>(query, key_, value, X_bf);
    repack_w<<<dim3(16, 16, 3), 256, 0, stream>>>(Wq, Wk, Wv, WT_bf);
    repack_wo<<<dim3(16, 16), 256, 0, stream>>>(Wo, WoT_bf);

    gemm_qkv<<<dim3(32, 8, 3), 256, 0, stream>>>(X_bf, WT_bf, bq, bk, bv, qkv_bf);
    v_transpose<<<dim3(8, 32), 256, 0, stream>>>(qkv_bf + 2 * per, vT_bf);

    attn_kernel<<<512, 512, 0, stream>>>(qkv_bf, qkv_bf + per, vT_bf, cat_bf);

    gemm_out<<<dim3(32, 8), 256, 0, stream>>>(cat_bf, WoT_bf, bo, out);
}

// Round 8
// 249.283 us; speedup vs baseline: 9.5454x; 1.1022x over previous
//
#include <hip/hip_runtime.h>
#include <hip/hip_bf16.h>
#include <math.h>

#define NB 2
#define NS 2048
#define ND 1024
#define NH 16
#define DH 64
#define MROWS (NB*NS)     // 4096
#define NCOLS (NH*DH)     // 1024

typedef __attribute__((ext_vector_type(8))) short bf16x8;
typedef __attribute__((ext_vector_type(4))) float f32x4;
typedef __attribute__((ext_vector_type(16))) float f32x16;
typedef __attribute__((ext_vector_type(4))) unsigned short ushort4t;
typedef __attribute__((ext_vector_type(8))) unsigned short ushort8t;
typedef unsigned short ushort;

extern "C" __device__ float __ocml_native_exp2_f32(float);
#define EXP2F(x) __ocml_native_exp2_f32(x)
#define LOG2E 1.44269504088896f

// HW bf16 convert (v_cvt_pk_bf16_f32 on gfx950)
static __device__ __forceinline__ ushort f2bf(float f) {
    union { __hip_bfloat16 b; ushort u; } cv;
    cv.b = __hip_bfloat16(f);
    return cv.u;
}

// packed pair convert: low16 = bf16(a), high16 = bf16(b)
static __device__ __forceinline__ unsigned cvtpk(float a, float b) {
    unsigned r;
    asm("v_cvt_pk_bf16_f32 %0, %1, %2" : "=v"(r) : "v"(a), "v"(b));
    return r;
}

static __device__ __forceinline__ void gld_lds16(const void* g, void* l) {
    __builtin_amdgcn_global_load_lds(
        (const __attribute__((address_space(1))) void*)g,
        (__attribute__((address_space(3))) void*)l, 16, 0, 0);
}

// ---------------- prep: X (q,k,v inputs) fp32 -> bf16 ----------------
__global__ __launch_bounds__(256) void convert_x(
    const float* __restrict__ q, const float* __restrict__ k,
    const float* __restrict__ v, ushort* __restrict__ X_bf)
{
    const size_t n1 = (size_t)MROWS * ND;
    const size_t off = ((size_t)blockIdx.x * 256 + threadIdx.x) * 8;
    const float* srcs[3] = {q, k, v};
    #pragma unroll
    for (int p = 0; p < 3; ++p) {
        float4 a = *(const float4*)(srcs[p] + off);
        float4 b = *(const float4*)(srcs[p] + off + 4);
        ushort8t w;
        w[0]=f2bf(a.x); w[1]=f2bf(a.y); w[2]=f2bf(a.z); w[3]=f2bf(a.w);
        w[4]=f2bf(b.x); w[5]=f2bf(b.y); w[6]=f2bf(b.z); w[7]=f2bf(b.w);
        *(ushort8t*)(X_bf + (size_t)p * n1 + off) = w;
    }
}

// ---------------- prep: Wq/Wk/Wv [H][D][64] -> bf16 W^T [p][h*64+e][d] ----------------
__global__ __launch_bounds__(256) void repack_w(
    const float* __restrict__ Wq, const float* __restrict__ Wk,
    const float* __restrict__ Wv, ushort* __restrict__ WT_bf)
{
    const int p = blockIdx.z;
    const float* W = (p == 0) ? Wq : (p == 1) ? Wk : Wv;
    const int h = blockIdx.y, d0 = blockIdx.x * 64;
    __shared__ float tile[64][65];
    const int t = threadIdx.x;
    {
        const int i = t >> 2, e0 = (t & 3) * 16;
        const float* src = W + ((size_t)h * ND + d0 + i) * DH + e0;
        #pragma unroll
        for (int u = 0; u < 4; ++u) {
            float4 v4 = ((const float4*)src)[u];
            tile[i][e0 + u*4 + 0] = v4.x; tile[i][e0 + u*4 + 1] = v4.y;
            tile[i][e0 + u*4 + 2] = v4.z; tile[i][e0 + u*4 + 3] = v4.w;
        }
    }
    __syncthreads();
    {
        const int e = t >> 2, dc = (t & 3) * 16;
        ushort* dst = WT_bf + ((size_t)p * NCOLS + h * 64 + e) * ND + d0 + dc;
        ushort8t w0, w1;
        #pragma unroll
        for (int u = 0; u < 8; ++u) { w0[u] = f2bf(tile[dc+u][e]); w1[u] = f2bf(tile[dc+8+u][e]); }
        *(ushort8t*)dst = w0;
        *(ushort8t*)(dst + 8) = w1;
    }
}

// ---------------- prep: Wo [1024][1024] -> bf16 Wo^T [c][f] ----------------
__global__ __launch_bounds__(256) void repack_wo(
    const float* __restrict__ Wo, ushort* __restrict__ WoT_bf)
{
    const int f0 = blockIdx.x * 64, c0 = blockIdx.y * 64;
    __shared__ float tile[64][65];
    const int t = threadIdx.x;
    {
        const int i = t >> 2, j0 = (t & 3) * 16;
        const float* src = Wo + (size_t)(f0 + i) * ND + c0 + j0;
        #pragma unroll
        for (int u = 0; u < 4; ++u) {
            float4 v4 = ((const float4*)src)[u];
            tile[i][j0 + u*4 + 0] = v4.x; tile[i][j0 + u*4 + 1] = v4.y;
            tile[i][j0 + u*4 + 2] = v4.z; tile[i][j0 + u*4 + 3] = v4.w;
        }
    }
    __syncthreads();
    {
        const int cl = t >> 2, fc = (t & 3) * 16;
        ushort* dst = WoT_bf + (size_t)(c0 + cl) * ND + f0 + fc;
        ushort8t w0, w1;
        #pragma unroll
        for (int u = 0; u < 8; ++u) { w0[u] = f2bf(tile[fc+u][cl]); w1[u] = f2bf(tile[fc+8+u][cl]); }
        *(ushort8t*)dst = w0;
        *(ushort8t*)(dst + 8) = w1;
    }
}

// ---------------- Kernel: QKV projection GEMM, bf16 MFMA ----------------
// Q output pre-scaled by (1/8)*log2(e) so attention softmax runs in exp2 domain.
__global__ __launch_bounds__(256) void gemm_qkv(
    const ushort* __restrict__ X_bf, const ushort* __restrict__ WT_bf,
    const float* __restrict__ bq, const float* __restrict__ bk,
    const float* __restrict__ bv, ushort* __restrict__ qkv_bf)
{
    const int p = blockIdx.z;
    const float* bias = (p == 0) ? bq : (p == 1) ? bk : bv;
    const float scale = (p == 0) ? 0.125f * LOG2E : 1.0f;
    const int m0 = blockIdx.x * 128, n0 = blockIdx.y * 128;
    const int t = threadIdx.x, wid = t >> 6, lane = t & 63;
    const int wr = wid >> 1, wc = wid & 1;
    const int c = lane & 15, g = lane >> 4;

    __shared__ ushort ldsA[128 * 64];
    __shared__ ushort ldsB[128 * 64];

    const ushort* Ag = X_bf + (size_t)p * MROWS * ND + (size_t)m0 * ND;
    const ushort* Bg = WT_bf + (size_t)p * NCOLS * ND + (size_t)n0 * ND;

    f32x4 acc[4][4];
    #pragma unroll
    for (int m = 0; m < 4; ++m)
        #pragma unroll
        for (int n = 0; n < 4; ++n)
            acc[m][n] = (f32x4){0.f, 0.f, 0.f, 0.f};

    for (int k0 = 0; k0 < ND; k0 += 64) {
        __syncthreads();
        #pragma unroll
        for (int call = 0; call < 4; ++call) {
            const int chb = wid * 256 + call * 64;
            const int ch = chb + lane;
            const int row = ch >> 3, c16 = ch & 7;
            gld_lds16(Ag + (size_t)row * ND + k0 + c16 * 8, ldsA + (size_t)ch * 8);
            gld_lds16(Bg + (size_t)row * ND + k0 + c16 * 8, ldsB + (size_t)ch * 8);
        }
        __syncthreads();
        #pragma unroll
        for (int kc = 0; kc < 2; ++kc) {
            bf16x8 af[4], bfr[4];
            #pragma unroll
            for (int m = 0; m < 4; ++m)
                af[m] = *(const bf16x8*)(ldsA + (wr*64 + m*16 + c) * 64 + kc*32 + g*8);
            #pragma unroll
            for (int n = 0; n < 4; ++n)
                bfr[n] = *(const bf16x8*)(ldsB + (wc*64 + n*16 + c) * 64 + kc*32 + g*8);
            #pragma unroll
            for (int m = 0; m < 4; ++m)
                #pragma unroll
                for (int n = 0; n < 4; ++n)
                    acc[m][n] = __builtin_amdgcn_mfma_f32_16x16x32_bf16(af[m], bfr[n], acc[m][n], 0, 0, 0);
        }
    }

    ushort* dst = qkv_bf + (size_t)p * ((size_t)NB * NH * NS * DH);
    #pragma unroll
    for (int m = 0; m < 4; ++m) {
        const int gr0 = m0 + wr*64 + m*16 + g*4;
        #pragma unroll
        for (int n = 0; n < 4; ++n) {
            const int gc = n0 + wc*64 + n*16 + c;
            const int h = gc >> 6, e = gc & 63;
            const float bv_ = bias[gc];
            #pragma unroll
            for (int j = 0; j < 4; ++j) {
                const int r = gr0 + j;
                const int b = r >> 11, s = r & (NS - 1);
                dst[(((size_t)b * NH + h) * NS + s) * DH + e] = f2bf((acc[m][n][j] + bv_) * scale);
            }
        }
    }
}

// ---------------- V transpose: [bh][s][64] -> [bh][e][S] ----------------
__global__ __launch_bounds__(256) void v_transpose(
    const ushort* __restrict__ v_bf, ushort* __restrict__ vT_bf)
{
    const int bh = blockIdx.y, s0 = blockIdx.x * 256;
    __shared__ ushort tile[256][72];
    const int t = threadIdx.x;
    const ushort* src = v_bf + ((size_t)bh * NS + s0) * DH;
    #pragma unroll
    for (int u = 0; u < 8; ++u) {
        const int idx = u * 256 + t;
        const int row = idx >> 3, cc = (idx & 7) * 8;
        *(ushort8t*)&tile[row][cc] = *(const ushort8t*)(src + (size_t)row * DH + cc);
    }
    __syncthreads();
    const int e = t >> 2, sc = (t & 3) * 64;
    ushort* dst = vT_bf + ((size_t)bh * DH + e) * NS + s0 + sc;
    #pragma unroll
    for (int u = 0; u < 8; ++u) {
        ushort8t w;
        #pragma unroll
        for (int x = 0; x < 8; ++x) w[x] = tile[sc + u*8 + x][e];
        *(ushort8t*)(dst + u * 8) = w;
    }
}

// ---------------- Kernel: flash attention, swapped 32x32 MFMA, in-register softmax ----
// grid: 512 1D blocks (XCD-mapped), block: 256 (4 waves, 32 q-rows each).
// S^T = mfma(K, Q): lane owns one q-col, 32 key-values in regs -> lane-local softmax.
// P packed in-register (cvt_pk + permlane32_swap) -> PV: O^T = mfma(V^T, P^T).
// LDS: K dbuf 2x8K | VT dbuf 2x8K = 32768 B (no P buffer).
__global__ __launch_bounds__(256) void attn_kernel(
    const ushort* __restrict__ q_bf, const ushort* __restrict__ k_bf,
    const ushort* __restrict__ vT_bf, ushort* __restrict__ cat_bf)
{
    __shared__ __attribute__((aligned(16))) char smem[32768];
    const int t = threadIdx.x;
    const int wid = t >> 6, lane = t & 63;
    const int ql = lane & 31;        // q column within wave tile
    const int hi = lane >> 5;        // half-wave

    // XCD-aware block -> (bh, qx): 4 heads per XCD, 16 q-blocks of 128 rows per head
    const int linear = blockIdx.x;          // 0..511
    const int xcd = linear & 7;
    const int idx = linear >> 3;            // 0..63
    const int bh = xcd * 4 + (idx >> 4);
    const int qx = idx & 15;
    const int qrow0 = qx * 128 + wid * 32;

    // Q B-fragments: lane holds Q[qrow0+ql][ds*16 + hi*8 + j], j=0..7
    bf16x8 qf[4];
    {
        const char* qp = (const char*)(q_bf + ((size_t)bh * NS + qrow0 + ql) * DH);
        #pragma unroll
        for (int ds = 0; ds < 4; ++ds)
            qf[ds] = *(const bf16x8*)(qp + ds * 32 + hi * 16);
    }

    f32x16 o_acc[2];
    #pragma unroll
    for (int et = 0; et < 2; ++et)
        #pragma unroll
        for (int i = 0; i < 16; ++i)
            o_acc[et][i] = 0.f;
    float m = -INFINITY, lsum = 0.f;

    const char* kg = (const char*)(k_bf + (size_t)bh * NS * DH);
    const char* vg = (const char*)(vT_bf + (size_t)bh * DH * NS);

    // staging: 2 chunks of 16B for K and for V per thread
    const int ch0 = t * 2;
    const int row0 = ch0 >> 3, c16a = ch0 & 7;
    const int c16b = c16a + 1;
    const int swz0 = (c16a * 16) ^ ((row0 & 7) << 4);
    const int swz1 = (c16b * 16) ^ ((row0 & 7) << 4);

    ushort8t kr0, kr1, vr0, vr1;

    #define ATTN_LOAD(JT) do { \
        kr0 = *(const ushort8t*)(kg + (size_t)((JT) + row0) * 128 + c16a * 16); \
        kr1 = *(const ushort8t*)(kg + (size_t)((JT) + row0) * 128 + c16b * 16); \
        vr0 = *(const ushort8t*)(vg + (size_t)row0 * (NS*2) + (size_t)((JT) + c16a*8) * 2); \
        vr1 = *(const ushort8t*)(vg + (size_t)row0 * (NS*2) + (size_t)((JT) + c16b*8) * 2); \
    } while (0)

    #define ATTN_STORE(BUF) do { \
        char* Kd = smem + (BUF) * 8192; \
        char* Vd = smem + 16384 + (BUF) * 8192; \
        *(ushort8t*)(Kd + row0 * 128 + swz0) = kr0; \
        *(ushort8t*)(Kd + row0 * 128 + swz1) = kr1; \
        *(ushort8t*)(Vd + row0 * 128 + swz0) = vr0; \
        *(ushort8t*)(Vd + row0 * 128 + swz1) = vr1; \
    } while (0)

    ATTN_LOAD(0);
    ATTN_STORE(0);
    __syncthreads();
    int cur = 0;

    for (int jt = 0; jt < NS; jt += 64) {
        ATTN_LOAD((jt + 64) & (NS - 1));

        const char* Ks  = smem + cur * 8192;
        const char* VTs = smem + 16384 + cur * 8192;

        // QK^T swapped: s_acc[kt] = S^T[key = kt*32 + coded][q = ql]
        f32x16 s_acc[2];
        #pragma unroll
        for (int kt = 0; kt < 2; ++kt)
            #pragma unroll
            for (int i = 0; i < 16; ++i)
                s_acc[kt][i] = 0.f;
        __builtin_amdgcn_s_setprio(1);
        #pragma unroll
        for (int ds = 0; ds < 4; ++ds) {
            #pragma unroll
            for (int kt = 0; kt < 2; ++kt) {
                const int key = kt * 32 + ql;
                bf16x8 kf = *(const bf16x8*)(Ks + key * 128 + ((ds*32 + hi*16) ^ ((key & 7) << 4)));
                s_acc[kt] = __builtin_amdgcn_mfma_f32_32x32x16_bf16(kf, qf[ds], s_acc[kt], 0, 0, 0);
            }
        }
        __builtin_amdgcn_s_setprio(0);

        // lane-local online softmax (exp2 domain, defer-max thr 11.5)
        float tm = -INFINITY;
        #pragma unroll
        for (int kt = 0; kt < 2; ++kt)
            #pragma unroll
            for (int i = 0; i < 16; ++i)
                tm = fmaxf(tm, s_acc[kt][i]);
        if (!__all(tm <= m + 11.5f)) {
            const float tm2 = fmaxf(tm, __shfl_xor(tm, 32));
            const float mnew = fmaxf(m, tm2);
            const float sc = EXP2F(m - mnew);
            lsum *= sc;
            #pragma unroll
            for (int et = 0; et < 2; ++et)
                #pragma unroll
                for (int i = 0; i < 16; ++i)
                    o_acc[et][i] *= sc;
            m = mnew;
        }

        float rs = 0.f;
        #pragma unroll
        for (int kt = 0; kt < 2; ++kt) {
            float pe[16];
            #pragma unroll
            for (int i = 0; i < 16; ++i) {
                pe[i] = EXP2F(s_acc[kt][i] - m);
                rs += pe[i];
            }
            // build PV B-fragments for ks = 2kt (keys +0..15) and 2kt+1 (keys +16..31)
            unsigned a0 = cvtpk(pe[0],  pe[1]);
            unsigned a1 = cvtpk(pe[2],  pe[3]);
            unsigned b0 = cvtpk(pe[4],  pe[5]);
            unsigned b1 = cvtpk(pe[6],  pe[7]);
            asm volatile("v_permlane32_swap_b32 %0, %1" : "+v"(a0), "+v"(b0));
            asm volatile("v_permlane32_swap_b32 %0, %1" : "+v"(a1), "+v"(b1));
            unsigned c0 = cvtpk(pe[8],  pe[9]);
            unsigned c1 = cvtpk(pe[10], pe[11]);
            unsigned d0 = cvtpk(pe[12], pe[13]);
            unsigned d1 = cvtpk(pe[14], pe[15]);
            asm volatile("v_permlane32_swap_b32 %0, %1" : "+v"(c0), "+v"(d0));
            asm volatile("v_permlane32_swap_b32 %0, %1" : "+v"(c1), "+v"(d1));
            union { bf16x8 v; unsigned u[4]; } B0, B1;
            B0.u[0] = a0; B0.u[1] = a1; B0.u[2] = b0; B0.u[3] = b1;
            B1.u[0] = c0; B1.u[1] = c1; B1.u[2] = d0; B1.u[3] = d1;

            __builtin_amdgcn_s_setprio(1);
            #pragma unroll
            for (int et = 0; et < 2; ++et) {
                const int e = et * 32 + ql;
                bf16x8 vf0 = *(const bf16x8*)(VTs + e * 128 + (((2*kt)   * 32 + hi*16) ^ ((e & 7) << 4)));
                o_acc[et] = __builtin_amdgcn_mfma_f32_32x32x16_bf16(vf0, B0.v, o_acc[et], 0, 0, 0);
                bf16x8 vf1 = *(const bf16x8*)(VTs + e * 128 + (((2*kt+1) * 32 + hi*16) ^ ((e & 7) << 4)));
                o_acc[et] = __builtin_amdgcn_mfma_f32_32x32x16_bf16(vf1, B1.v, o_acc[et], 0, 0, 0);
            }
            __builtin_amdgcn_s_setprio(0);
        }
        lsum += rs;

        ATTN_STORE(cur ^ 1);
        __syncthreads();
        cur ^= 1;
    }

    // combine the two half-wave partial sums for each q-row
    lsum += __shfl_xor(lsum, 32);
    const float inv = 1.0f / lsum;

    // write O^T: lane = q-row (ql), values cover e = et*32 + rgrp*8 + hi*4 + 0..3
    const int b = bh >> 4, hh = bh & 15;
    const int s = qrow0 + ql;
    ushort* op = cat_bf + ((size_t)b * NS + s) * NCOLS + hh * DH;
    #pragma unroll
    for (int et = 0; et < 2; ++et) {
        #pragma unroll
        for (int rgrp = 0; rgrp < 4; ++rgrp) {
            uint2 wv;
            wv.x = cvtpk(o_acc[et][rgrp*4+0] * inv, o_acc[et][rgrp*4+1] * inv);
            wv.y = cvtpk(o_acc[et][rgrp*4+2] * inv, o_acc[et][rgrp*4+3] * inv);
            *(uint2*)(op + et*32 + rgrp*8 + hi*4) = wv;
        }
    }
    #undef ATTN_LOAD
    #undef ATTN_STORE
}

// ---------------- Kernel: output GEMM, bf16 MFMA, fp32 out ----------------
__global__ __launch_bounds__(256) void gemm_out(
    const ushort* __restrict__ cat_bf, const ushort* __restrict__ WoT_bf,
    const float* __restrict__ bo, float* __restrict__ out)
{
    const int m0 = blockIdx.x * 128, n0 = blockIdx.y * 128;
    const int t = threadIdx.x, wid = t >> 6, lane = t & 63;
    const int wr = wid >> 1, wc = wid & 1;
    const int c = lane & 15, g = lane >> 4;

    __shared__ ushort ldsA[128 * 64];
    __shared__ ushort ldsB[128 * 64];

    const ushort* Ag = cat_bf + (size_t)m0 * ND;
    const ushort* Bg = WoT_bf + (size_t)n0 * ND;

    f32x4 acc[4][4];
    #pragma unroll
    for (int m = 0; m < 4; ++m)
        #pragma unroll
        for (int n = 0; n < 4; ++n)
            acc[m][n] = (f32x4){0.f, 0.f, 0.f, 0.f};

    for (int k0 = 0; k0 < ND; k0 += 64) {
        __syncthreads();
        #pragma unroll
        for (int call = 0; call < 4; ++call) {
            const int chb = wid * 256 + call * 64;
            const int ch = chb + lane;
            const int row = ch >> 3, c16 = ch & 7;
            gld_lds16(Ag + (size_t)row * ND + k0 + c16 * 8, ldsA + (size_t)ch * 8);
            gld_lds16(Bg + (size_t)row * ND + k0 + c16 * 8, ldsB + (size_t)ch * 8);
        }
        __syncthreads();
        #pragma unroll
        for (int kc = 0; kc < 2; ++kc) {
            bf16x8 af[4], bfr[4];
            #pragma unroll
            for (int m = 0; m < 4; ++m)
                af[m] = *(const bf16x8*)(ldsA + (wr*64 + m*16 + c) * 64 + kc*32 + g*8);
            #pragma unroll
            for (int n = 0; n < 4; ++n)
                bfr[n] = *(const bf16x8*)(ldsB + (wc*64 + n*16 + c) * 64 + kc*32 + g*8);
            #pragma unroll
            for (int m = 0; m < 4; ++m)
                #pragma unroll
                for (int n = 0; n < 4; ++n)
                    acc[m][n] = __builtin_amdgcn_mfma_f32_16x16x32_bf16(af[m], bfr[n], acc[m][n], 0, 0, 0);
        }
    }

    #pragma unroll
    for (int m = 0; m < 4; ++m) {
        const int gr0 = m0 + wr*64 + m*16 + g*4;
        #pragma unroll
        for (int n = 0; n < 4; ++n) {
            const int gc = n0 + wc*64 + n*16 + c;
            const float bv_ = bo[gc];
            #pragma unroll
            for (int j = 0; j < 4; ++j)
                out[(size_t)(gr0 + j) * ND + gc] = acc[m][n][j] + bv_;
        }
    }
}

extern "C" void kernel_launch(void* const* d_in, const int* in_sizes, int n_in,
                              void* d_out, int out_size, void* d_ws, size_t ws_size,
                              hipStream_t stream) {
    const float* query = (const float*)d_in[0];
    const float* key_  = (const float*)d_in[1];
    const float* value = (const float*)d_in[2];
    const float* Wq = (const float*)d_in[3];
    const float* bq = (const float*)d_in[4];
    const float* Wk = (const float*)d_in[5];
    const float* bk = (const float*)d_in[6];
    const float* Wv = (const float*)d_in[7];
    const float* bv = (const float*)d_in[8];
    const float* Wo = (const float*)d_in[9];
    const float* bo = (const float*)d_in[10];
    float* out = (float*)d_out;

    const size_t per = (size_t)NB * NH * NS * DH;   // 4.19M
    const size_t xsz = (size_t)MROWS * ND;          // 4.19M

    ushort* X_bf   = (ushort*)d_ws;                 // 3*xsz
    ushort* qkv_bf = X_bf + 3 * xsz;                // 3*per  (q | k | v)
    ushort* vT_bf  = qkv_bf + 3 * per;              // per
    ushort* WT_bf  = vT_bf + per;                   // 3*1024*1024
    ushort* WoT_bf = WT_bf + (size_t)3 * ND * NCOLS;// 1024*1024
    ushort* cat_bf = X_bf;                          // alias: X dead after gemm_qkv

    convert_x<<<2048, 256, 0, stream>>>(query, key_, value, X_bf);
    repack_w<<<dim3(16, 16, 3), 256, 0, stream>>>(Wq, Wk, Wv, WT_bf);
    repack_wo<<<dim3(16, 16), 256, 0, stream>>>(Wo, WoT_bf);

    gemm_qkv<<<dim3(32, 8, 3), 256, 0, stream>>>(X_bf, WT_bf, bq, bk, bv, qkv_bf);
    v_transpose<<<dim3(8, 32), 256, 0, stream>>>(qkv_bf + 2 * per, vT_bf);

    attn_kernel<<<512, 256, 0, stream>>>(qkv_bf, qkv_bf + per, vT_bf, cat_bf);

    gemm_out<<<dim3(32, 8), 256, 0, stream>>>(cat_bf, WoT_bf, bo, out);
}

// Round 9
// 238.501 us; speedup vs baseline: 9.9769x; 1.0452x over previous
//
#include <hip/hip_runtime.h>
#include <hip/hip_bf16.h>
#include <math.h>

#define NB 2
#define NS 2048
#define ND 1024
#define NH 16
#define DH 64
#define MROWS (NB*NS)     // 4096
#define NCOLS (NH*DH)     // 1024

typedef __attribute__((ext_vector_type(8))) short bf16x8;
typedef __attribute__((ext_vector_type(4))) float f32x4;
typedef __attribute__((ext_vector_type(16))) float f32x16;
typedef __attribute__((ext_vector_type(8))) unsigned short ushort8t;
typedef unsigned short ushort;

extern "C" __device__ float __ocml_native_exp2_f32(float);
#define EXP2F(x) __ocml_native_exp2_f32(x)
#define LOG2E 1.44269504088896f

// HW bf16 convert (v_cvt_pk_bf16_f32 on gfx950)
static __device__ __forceinline__ ushort f2bf(float f) {
    union { __hip_bfloat16 b; ushort u; } cv;
    cv.b = __hip_bfloat16(f);
    return cv.u;
}

// packed pair convert: low16 = bf16(a), high16 = bf16(b)
static __device__ __forceinline__ unsigned cvtpk(float a, float b) {
    unsigned r;
    asm("v_cvt_pk_bf16_f32 %0, %1, %2" : "=v"(r) : "v"(a), "v"(b));
    return r;
}

static __device__ __forceinline__ float fmax3(float a, float b, float c) {
    return fmaxf(fmaxf(a, b), c);   // clang fuses to v_max3_f32
}

static __device__ __forceinline__ void gld_lds16(const void* g, void* l) {
    __builtin_amdgcn_global_load_lds(
        (const __attribute__((address_space(1))) void*)g,
        (__attribute__((address_space(3))) void*)l, 16, 0, 0);
}

// ---------------- merged prep kernel ----------------
// blocks [0,2048): X fp32->bf16 ; [2048,2816): Wq/Wk/Wv repack ; [2816,3072): Wo repack
__global__ __launch_bounds__(256) void prep_kernel(
    const float* __restrict__ q, const float* __restrict__ k,
    const float* __restrict__ v, ushort* __restrict__ X_bf,
    const float* __restrict__ Wq, const float* __restrict__ Wk,
    const float* __restrict__ Wv, ushort* __restrict__ WT_bf,
    const float* __restrict__ Wo, ushort* __restrict__ WoT_bf)
{
    const int bx = blockIdx.x;
    const int t = threadIdx.x;
    __shared__ float tile[64][65];

    if (bx < 2048) {
        const size_t n1 = (size_t)MROWS * ND;
        const size_t off = ((size_t)bx * 256 + t) * 8;
        const float* srcs[3] = {q, k, v};
        #pragma unroll
        for (int p = 0; p < 3; ++p) {
            float4 a = *(const float4*)(srcs[p] + off);
            float4 b = *(const float4*)(srcs[p] + off + 4);
            ushort8t w;
            w[0]=f2bf(a.x); w[1]=f2bf(a.y); w[2]=f2bf(a.z); w[3]=f2bf(a.w);
            w[4]=f2bf(b.x); w[5]=f2bf(b.y); w[6]=f2bf(b.z); w[7]=f2bf(b.w);
            *(ushort8t*)(X_bf + (size_t)p * n1 + off) = w;
        }
    } else if (bx < 2816) {
        const int i2 = bx - 2048;
        const int p = i2 >> 8;                 // /256
        const int r = i2 & 255;
        const int h = r >> 4, d0 = (r & 15) * 64;
        const float* W = (p == 0) ? Wq : (p == 1) ? Wk : Wv;
        {
            const int i = t >> 2, e0 = (t & 3) * 16;
            const float* src = W + ((size_t)h * ND + d0 + i) * DH + e0;
            #pragma unroll
            for (int u = 0; u < 4; ++u) {
                float4 v4 = ((const float4*)src)[u];
                tile[i][e0 + u*4 + 0] = v4.x; tile[i][e0 + u*4 + 1] = v4.y;
                tile[i][e0 + u*4 + 2] = v4.z; tile[i][e0 + u*4 + 3] = v4.w;
            }
        }
        __syncthreads();
        {
            const int e = t >> 2, dc = (t & 3) * 16;
            ushort* dst = WT_bf + ((size_t)p * NCOLS + h * 64 + e) * ND + d0 + dc;
            ushort8t w0, w1;
            #pragma unroll
            for (int u = 0; u < 8; ++u) { w0[u] = f2bf(tile[dc+u][e]); w1[u] = f2bf(tile[dc+8+u][e]); }
            *(ushort8t*)dst = w0;
            *(ushort8t*)(dst + 8) = w1;
        }
    } else {
        const int i3 = bx - 2816;
        const int f0 = (i3 & 15) * 64, c0 = (i3 >> 4) * 64;
        {
            const int i = t >> 2, j0 = (t & 3) * 16;
            const float* src = Wo + (size_t)(f0 + i) * ND + c0 + j0;
            #pragma unroll
            for (int u = 0; u < 4; ++u) {
                float4 v4 = ((const float4*)src)[u];
                tile[i][j0 + u*4 + 0] = v4.x; tile[i][j0 + u*4 + 1] = v4.y;
                tile[i][j0 + u*4 + 2] = v4.z; tile[i][j0 + u*4 + 3] = v4.w;
            }
        }
        __syncthreads();
        {
            const int cl = t >> 2, fc = (t & 3) * 16;
            ushort* dst = WoT_bf + (size_t)(c0 + cl) * ND + f0 + fc;
            ushort8t w0, w1;
            #pragma unroll
            for (int u = 0; u < 8; ++u) { w0[u] = f2bf(tile[fc+u][cl]); w1[u] = f2bf(tile[fc+8+u][cl]); }
            *(ushort8t*)dst = w0;
            *(ushort8t*)(dst + 8) = w1;
        }
    }
}

// ---------------- Kernel: QKV projection GEMM, bf16 MFMA ----------------
// p=0: Q (scaled by 0.125*log2e) -> [bh][s][64]  (LDS-bounce coalesced epilogue)
// p=1: K -> [bh][s][64]                           (LDS-bounce coalesced epilogue)
// p=2: V -> V^T [bh][e][S] directly               (packed uint2, 4 consecutive s)
__global__ __launch_bounds__(256) void gemm_qkv(
    const ushort* __restrict__ X_bf, const ushort* __restrict__ WT_bf,
    const float* __restrict__ bq, const float* __restrict__ bk,
    const float* __restrict__ bv, ushort* __restrict__ qkv_bf,
    ushort* __restrict__ vT_bf)
{
    const int p = blockIdx.z;
    const float* bias = (p == 0) ? bq : (p == 1) ? bk : bv;
    const float scale = (p == 0) ? 0.125f * LOG2E : 1.0f;
    const int m0 = blockIdx.x * 128, n0 = blockIdx.y * 128;
    const int t = threadIdx.x, wid = t >> 6, lane = t & 63;
    const int wr = wid >> 1, wc = wid & 1;
    const int c = lane & 15, g = lane >> 4;

    __shared__ ushort ldsAB[2 * 128 * 64];   // A | B staging; reused as 128x128 epilogue tile
    ushort* ldsA = ldsAB;
    ushort* ldsB = ldsAB + 128 * 64;

    const ushort* Ag = X_bf + (size_t)p * MROWS * ND + (size_t)m0 * ND;
    const ushort* Bg = WT_bf + (size_t)p * NCOLS * ND + (size_t)n0 * ND;

    f32x4 acc[4][4];
    #pragma unroll
    for (int m = 0; m < 4; ++m)
        #pragma unroll
        for (int n = 0; n < 4; ++n)
            acc[m][n] = (f32x4){0.f, 0.f, 0.f, 0.f};

    for (int k0 = 0; k0 < ND; k0 += 64) {
        __syncthreads();
        #pragma unroll
        for (int call = 0; call < 4; ++call) {
            const int ch = wid * 256 + call * 64 + lane;
            const int row = ch >> 3, c16 = ch & 7;
            gld_lds16(Ag + (size_t)row * ND + k0 + c16 * 8, ldsA + (size_t)ch * 8);
            gld_lds16(Bg + (size_t)row * ND + k0 + c16 * 8, ldsB + (size_t)ch * 8);
        }
        __syncthreads();
        #pragma unroll
        for (int kc = 0; kc < 2; ++kc) {
            bf16x8 af[4], bfr[4];
            #pragma unroll
            for (int m = 0; m < 4; ++m)
                af[m] = *(const bf16x8*)(ldsA + (wr*64 + m*16 + c) * 64 + kc*32 + g*8);
            #pragma unroll
            for (int n = 0; n < 4; ++n)
                bfr[n] = *(const bf16x8*)(ldsB + (wc*64 + n*16 + c) * 64 + kc*32 + g*8);
            #pragma unroll
            for (int m = 0; m < 4; ++m)
                #pragma unroll
                for (int n = 0; n < 4; ++n)
                    acc[m][n] = __builtin_amdgcn_mfma_f32_16x16x32_bf16(af[m], bfr[n], acc[m][n], 0, 0, 0);
        }
    }

    if (p == 2) {
        // V^T direct: thread's 4 j-values are 4 consecutive s at fixed e
        #pragma unroll
        for (int m = 0; m < 4; ++m) {
            const int s0b = m0 + wr*64 + m*16 + g*4;
            const int b = s0b >> 11, sl = s0b & (NS - 1);
            #pragma unroll
            for (int n = 0; n < 4; ++n) {
                const int gc = n0 + wc*64 + n*16 + c;
                const int h = gc >> 6, e = gc & 63;
                const float bv_ = bias[gc];
                uint2 wv;
                wv.x = cvtpk(acc[m][n][0] + bv_, acc[m][n][1] + bv_);
                wv.y = cvtpk(acc[m][n][2] + bv_, acc[m][n][3] + bv_);
                *(uint2*)(vT_bf + ((size_t)(b * NH + h) * DH + e) * NS + sl) = wv;
            }
        }
    } else {
        // Q/K: LDS-bounce for coalesced 16B stores
        __syncthreads();   // all waves done reading ldsA/ldsB
        ushort* ldsC = ldsAB;   // 128 x 128 bf16 = 32 KB
        #pragma unroll
        for (int m = 0; m < 4; ++m)
            #pragma unroll
            for (int n = 0; n < 4; ++n) {
                const int col = wc*64 + n*16 + c;
                const float bv_ = bias[n0 + col];
                #pragma unroll
                for (int j = 0; j < 4; ++j) {
                    const int row = wr*64 + m*16 + g*4 + j;
                    ldsC[row * 128 + col] = f2bf((acc[m][n][j] + bv_) * scale);
                }
            }
        __syncthreads();
        ushort* dstbase = qkv_bf + (size_t)p * ((size_t)NB * NH * NS * DH);
        #pragma unroll
        for (int rr = 0; rr < 8; ++rr) {
            const int idx = rr * 256 + t;
            const int row = idx >> 4;        // 0..127
            const int col0 = (idx & 15) * 8; // 0..120
            const int gc = n0 + col0;
            const int h = gc >> 6, e0 = gc & 63;
            const int gr = m0 + row;
            const int b = gr >> 11, s = gr & (NS - 1);
            ushort8t w = *(ushort8t*)(ldsC + row * 128 + col0);
            *(ushort8t*)(dstbase + (((size_t)b * NH + h) * NS + s) * DH + e0) = w;
        }
    }
}

// ---------------- Kernel: flash attention, swapped 32x32 MFMA, in-register softmax ----
// grid: 512 1D blocks (XCD-mapped), block: 256 (4 waves, 32 q-rows each).
__global__ __launch_bounds__(256) void attn_kernel(
    const ushort* __restrict__ q_bf, const ushort* __restrict__ k_bf,
    const ushort* __restrict__ vT_bf, ushort* __restrict__ cat_bf)
{
    __shared__ __attribute__((aligned(16))) char smem[32768];
    const int t = threadIdx.x;
    const int wid = t >> 6, lane = t & 63;
    const int ql = lane & 31;
    const int hi = lane >> 5;

    const int linear = blockIdx.x;
    const int xcd = linear & 7;
    const int idx = linear >> 3;
    const int bh = xcd * 4 + (idx >> 4);
    const int qx = idx & 15;
    const int qrow0 = qx * 128 + wid * 32;

    bf16x8 qf[4];
    {
        const char* qp = (const char*)(q_bf + ((size_t)bh * NS + qrow0 + ql) * DH);
        #pragma unroll
        for (int ds = 0; ds < 4; ++ds)
            qf[ds] = *(const bf16x8*)(qp + ds * 32 + hi * 16);
    }

    f32x16 o_acc[2];
    #pragma unroll
    for (int et = 0; et < 2; ++et)
        #pragma unroll
        for (int i = 0; i < 16; ++i)
            o_acc[et][i] = 0.f;
    float m = -INFINITY, lsum = 0.f;

    const char* kg = (const char*)(k_bf + (size_t)bh * NS * DH);
    const char* vg = (const char*)(vT_bf + (size_t)bh * DH * NS);

    const int ch0 = t * 2;
    const int row0 = ch0 >> 3, c16a = ch0 & 7;
    const int c16b = c16a + 1;
    const int swz0 = (c16a * 16) ^ ((row0 & 7) << 4);
    const int swz1 = (c16b * 16) ^ ((row0 & 7) << 4);

    ushort8t kr0, kr1, vr0, vr1;

    #define ATTN_LOAD(JT) do { \
        kr0 = *(const ushort8t*)(kg + (size_t)((JT) + row0) * 128 + c16a * 16); \
        kr1 = *(const ushort8t*)(kg + (size_t)((JT) + row0) * 128 + c16b * 16); \
        vr0 = *(const ushort8t*)(vg + (size_t)row0 * (NS*2) + (size_t)((JT) + c16a*8) * 2); \
        vr1 = *(const ushort8t*)(vg + (size_t)row0 * (NS*2) + (size_t)((JT) + c16b*8) * 2); \
    } while (0)

    #define ATTN_STORE(BUF) do { \
        char* Kd = smem + (BUF) * 8192; \
        char* Vd = smem + 16384 + (BUF) * 8192; \
        *(ushort8t*)(Kd + row0 * 128 + swz0) = kr0; \
        *(ushort8t*)(Kd + row0 * 128 + swz1) = kr1; \
        *(ushort8t*)(Vd + row0 * 128 + swz0) = vr0; \
        *(ushort8t*)(Vd + row0 * 128 + swz1) = vr1; \
    } while (0)

    ATTN_LOAD(0);
    ATTN_STORE(0);
    __syncthreads();
    int cur = 0;

    for (int jt = 0; jt < NS; jt += 64) {
        ATTN_LOAD((jt + 64) & (NS - 1));

        const char* Ks  = smem + cur * 8192;
        const char* VTs = smem + 16384 + cur * 8192;

        f32x16 s_acc[2];
        #pragma unroll
        for (int kt = 0; kt < 2; ++kt)
            #pragma unroll
            for (int i = 0; i < 16; ++i)
                s_acc[kt][i] = 0.f;
        __builtin_amdgcn_s_setprio(1);
        #pragma unroll
        for (int ds = 0; ds < 4; ++ds) {
            #pragma unroll
            for (int kt = 0; kt < 2; ++kt) {
                const int key = kt * 32 + ql;
                bf16x8 kf = *(const bf16x8*)(Ks + key * 128 + ((ds*32 + hi*16) ^ ((key & 7) << 4)));
                s_acc[kt] = __builtin_amdgcn_mfma_f32_32x32x16_bf16(kf, qf[ds], s_acc[kt], 0, 0, 0);
            }
        }
        __builtin_amdgcn_s_setprio(0);

        // lane-local online softmax (exp2 domain, defer-max thr 11.5), v_max3 tree
        float tm = fmaxf(s_acc[0][0], s_acc[0][1]);
        #pragma unroll
        for (int i = 2; i < 16; i += 2) tm = fmax3(tm, s_acc[0][i], s_acc[0][i+1]);
        #pragma unroll
        for (int i = 0; i < 16; i += 2) tm = fmax3(tm, s_acc[1][i], s_acc[1][i+1]);
        if (!__all(tm <= m + 11.5f)) {
            const float tm2 = fmaxf(tm, __shfl_xor(tm, 32));
            const float mnew = fmaxf(m, tm2);
            const float sc = EXP2F(m - mnew);
            lsum *= sc;
            #pragma unroll
            for (int et = 0; et < 2; ++et)
                #pragma unroll
                for (int i = 0; i < 16; ++i)
                    o_acc[et][i] *= sc;
            m = mnew;
        }

        float rs = 0.f;
        #pragma unroll
        for (int kt = 0; kt < 2; ++kt) {
            float pe[16];
            #pragma unroll
            for (int i = 0; i < 16; ++i) {
                pe[i] = EXP2F(s_acc[kt][i] - m);
                rs += pe[i];
            }
            unsigned a0 = cvtpk(pe[0],  pe[1]);
            unsigned a1 = cvtpk(pe[2],  pe[3]);
            unsigned b0 = cvtpk(pe[4],  pe[5]);
            unsigned b1 = cvtpk(pe[6],  pe[7]);
            asm volatile("v_permlane32_swap_b32 %0, %1" : "+v"(a0), "+v"(b0));
            asm volatile("v_permlane32_swap_b32 %0, %1" : "+v"(a1), "+v"(b1));
            unsigned c0 = cvtpk(pe[8],  pe[9]);
            unsigned c1 = cvtpk(pe[10], pe[11]);
            unsigned d0 = cvtpk(pe[12], pe[13]);
            unsigned d1 = cvtpk(pe[14], pe[15]);
            asm volatile("v_permlane32_swap_b32 %0, %1" : "+v"(c0), "+v"(d0));
            asm volatile("v_permlane32_swap_b32 %0, %1" : "+v"(c1), "+v"(d1));
            union { bf16x8 v; unsigned u[4]; } B0, B1;
            B0.u[0] = a0; B0.u[1] = a1; B0.u[2] = b0; B0.u[3] = b1;
            B1.u[0] = c0; B1.u[1] = c1; B1.u[2] = d0; B1.u[3] = d1;

            __builtin_amdgcn_s_setprio(1);
            #pragma unroll
            for (int et = 0; et < 2; ++et) {
                const int e = et * 32 + ql;
                bf16x8 vf0 = *(const bf16x8*)(VTs + e * 128 + (((2*kt)   * 32 + hi*16) ^ ((e & 7) << 4)));
                o_acc[et] = __builtin_amdgcn_mfma_f32_32x32x16_bf16(vf0, B0.v, o_acc[et], 0, 0, 0);
                bf16x8 vf1 = *(const bf16x8*)(VTs + e * 128 + (((2*kt+1) * 32 + hi*16) ^ ((e & 7) << 4)));
                o_acc[et] = __builtin_amdgcn_mfma_f32_32x32x16_bf16(vf1, B1.v, o_acc[et], 0, 0, 0);
            }
            __builtin_amdgcn_s_setprio(0);
        }
        lsum += rs;

        ATTN_STORE(cur ^ 1);
        __syncthreads();
        cur ^= 1;
    }

    lsum += __shfl_xor(lsum, 32);
    const float inv = 1.0f / lsum;

    const int b = bh >> 4, hh = bh & 15;
    const int s = qrow0 + ql;
    ushort* op = cat_bf + ((size_t)b * NS + s) * NCOLS + hh * DH;
    #pragma unroll
    for (int et = 0; et < 2; ++et) {
        #pragma unroll
        for (int rgrp = 0; rgrp < 4; ++rgrp) {
            uint2 wv;
            wv.x = cvtpk(o_acc[et][rgrp*4+0] * inv, o_acc[et][rgrp*4+1] * inv);
            wv.y = cvtpk(o_acc[et][rgrp*4+2] * inv, o_acc[et][rgrp*4+3] * inv);
            *(uint2*)(op + et*32 + rgrp*8 + hi*4) = wv;
        }
    }
    #undef ATTN_LOAD
    #undef ATTN_STORE
}

// ---------------- Kernel: output GEMM, bf16 MFMA, fp32 out ----------------
__global__ __launch_bounds__(256) void gemm_out(
    const ushort* __restrict__ cat_bf, const ushort* __restrict__ WoT_bf,
    const float* __restrict__ bo, float* __restrict__ out)
{
    const int m0 = blockIdx.x * 128, n0 = blockIdx.y * 128;
    const int t = threadIdx.x, wid = t >> 6, lane = t & 63;
    const int wr = wid >> 1, wc = wid & 1;
    const int c = lane & 15, g = lane >> 4;

    __shared__ ushort ldsA[128 * 64];
    __shared__ ushort ldsB[128 * 64];

    const ushort* Ag = cat_bf + (size_t)m0 * ND;
    const ushort* Bg = WoT_bf + (size_t)n0 * ND;

    f32x4 acc[4][4];
    #pragma unroll
    for (int m = 0; m < 4; ++m)
        #pragma unroll
        for (int n = 0; n < 4; ++n)
            acc[m][n] = (f32x4){0.f, 0.f, 0.f, 0.f};

    for (int k0 = 0; k0 < ND; k0 += 64) {
        __syncthreads();
        #pragma unroll
        for (int call = 0; call < 4; ++call) {
            const int ch = wid * 256 + call * 64 + lane;
            const int row = ch >> 3, c16 = ch & 7;
            gld_lds16(Ag + (size_t)row * ND + k0 + c16 * 8, ldsA + (size_t)ch * 8);
            gld_lds16(Bg + (size_t)row * ND + k0 + c16 * 8, ldsB + (size_t)ch * 8);
        }
        __syncthreads();
        #pragma unroll
        for (int kc = 0; kc < 2; ++kc) {
            bf16x8 af[4], bfr[4];
            #pragma unroll
            for (int m = 0; m < 4; ++m)
                af[m] = *(const bf16x8*)(ldsA + (wr*64 + m*16 + c) * 64 + kc*32 + g*8);
            #pragma unroll
            for (int n = 0; n < 4; ++n)
                bfr[n] = *(const bf16x8*)(ldsB + (wc*64 + n*16 + c) * 64 + kc*32 + g*8);
            #pragma unroll
            for (int m = 0; m < 4; ++m)
                #pragma unroll
                for (int n = 0; n < 4; ++n)
                    acc[m][n] = __builtin_amdgcn_mfma_f32_16x16x32_bf16(af[m], bfr[n], acc[m][n], 0, 0, 0);
        }
    }

    #pragma unroll
    for (int m = 0; m < 4; ++m) {
        const int gr0 = m0 + wr*64 + m*16 + g*4;
        #pragma unroll
        for (int n = 0; n < 4; ++n) {
            const int gc = n0 + wc*64 + n*16 + c;
            const float bv_ = bo[gc];
            #pragma unroll
            for (int j = 0; j < 4; ++j)
                out[(size_t)(gr0 + j) * ND + gc] = acc[m][n][j] + bv_;
        }
    }
}

extern "C" void kernel_launch(void* const* d_in, const int* in_sizes, int n_in,
                              void* d_out, int out_size, void* d_ws, size_t ws_size,
                              hipStream_t stream) {
    const float* query = (const float*)d_in[0];
    const float* key_  = (const float*)d_in[1];
    const float* value = (const float*)d_in[2];
    const float* Wq = (const float*)d_in[3];
    const float* bq = (const float*)d_in[4];
    const float* Wk = (const float*)d_in[5];
    const float* bk = (const float*)d_in[6];
    const float* Wv = (const float*)d_in[7];
    const float* bv = (const float*)d_in[8];
    const float* Wo = (const float*)d_in[9];
    const float* bo = (const float*)d_in[10];
    float* out = (float*)d_out;

    const size_t per = (size_t)NB * NH * NS * DH;   // 4.19M
    const size_t xsz = (size_t)MROWS * ND;          // 4.19M

    ushort* X_bf   = (ushort*)d_ws;                 // 3*xsz
    ushort* qkv_bf = X_bf + 3 * xsz;                // q | k regions (3*per reserved)
    ushort* vT_bf  = qkv_bf + 3 * per;              // per
    ushort* WT_bf  = vT_bf + per;                   // 3*1024*1024
    ushort* WoT_bf = WT_bf + (size_t)3 * ND * NCOLS;// 1024*1024
    ushort* cat_bf = X_bf;                          // alias: X dead after gemm_qkv

    prep_kernel<<<3072, 256, 0, stream>>>(query, key_, value, X_bf,
                                          Wq, Wk, Wv, WT_bf, Wo, WoT_bf);

    gemm_qkv<<<dim3(32, 8, 3), 256, 0, stream>>>(X_bf, WT_bf, bq, bk, bv, qkv_bf, vT_bf);

    attn_kernel<<<512, 256, 0, stream>>>(qkv_bf, qkv_bf + per, vT_bf, cat_bf);

    gemm_out<<<dim3(32, 8), 256, 0, stream>>>(cat_bf, WoT_bf, bo, out);
}